// Round 1
// baseline (21130.200 us; speedup 1.0000x reference)
//
#include <hip/hip_runtime.h>
#include <math.h>

// ---------------- constants ----------------
#define NIMG 2
#define NCAND 4630
#define MAXDET 100
#define IMG_W_F 1216.0f
#define IMG_H_F 800.0f
#define SCORE_THR 0.05f
#define NMS_THR 0.5f
#define SCALE_CLAMP_F 4.135166556742356f  // log(1000/16)

#define TH 4
#define TW 16
#define CCH 16
#define COT 64

enum { MODE_RELU = 0, MODE_SIG = 1, MODE_RAW = 2 };

// ---------------- conv 3x3, Cin=256, SAME pad ----------------
// block: 256 thr = 16 co-quads x 16 pos-groups; tile: 64 co x (4x16) spatial
__global__ __launch_bounds__(256, 3)
void conv3x3_k(const float* __restrict__ x, const float* __restrict__ wt,
               const float* __restrict__ bias, float* __restrict__ y,
               int H, int W, int Cout, int mode)
{
  __shared__ __align__(16) float s_in[CCH][TH + 2][TW + 2];
  __shared__ __align__(16) float s_w[CCH][9][COT];

  const int tid = threadIdx.x;
  const int coq = tid & 15;        // co = 4*coq
  const int pg  = tid >> 4;        // 0..15
  const int r   = pg >> 2;         // tile row 0..3
  const int cg  = (pg & 3) << 2;   // tile col base 0,4,8,12

  const int w0 = blockIdx.x * TW;
  const int h0 = blockIdx.y * TH;
  const int CG = (Cout + COT - 1) / COT;
  const int n  = blockIdx.z / CG;
  const int cb = (blockIdx.z % CG) * COT;

  float acc[4][4];
#pragma unroll
  for (int q = 0; q < 4; ++q)
#pragma unroll
    for (int wi = 0; wi < 4; ++wi) acc[q][wi] = 0.f;

  const float* xn = x + (size_t)n * 256 * H * W;

  for (int c0 = 0; c0 < 256; c0 += CCH) {
    // stage input halo 16 x 6 x 18
    for (int idx = tid; idx < CCH * 6 * (TW + 2); idx += 256) {
      int c  = idx / (6 * (TW + 2));
      int rm = idx - c * (6 * (TW + 2));
      int i  = rm / (TW + 2);
      int j  = rm - i * (TW + 2);
      int hh = h0 - 1 + i;
      int ww = w0 - 1 + j;
      float v = 0.f;
      if ((unsigned)hh < (unsigned)H && (unsigned)ww < (unsigned)W)
        v = xn[((size_t)(c0 + c) * H + hh) * W + ww];
      s_in[c][i][j] = v;
    }
    // stage weights 16 x 9 x 64 (co fastest -> conflict-free LDS writes)
    for (int idx = tid; idx < CCH * 9 * COT; idx += 256) {
      int co  = idx & (COT - 1);
      int t   = idx >> 6;
      int c   = t / 9;
      int tap = t - c * 9;
      int coA = cb + co;
      float v = 0.f;
      if (coA < Cout) v = wt[(size_t)coA * 2304 + (size_t)(c0 + c) * 9 + tap];
      s_w[c][tap][co] = v;
    }
    __syncthreads();

#pragma unroll
    for (int c = 0; c < CCH; ++c) {
#pragma unroll
      for (int kh = 0; kh < 3; ++kh) {
        const float* row = &s_in[c][r + kh][cg];
        float in6[6];
#pragma unroll
        for (int j = 0; j < 6; ++j) in6[j] = row[j];
        float4 wv[3];
#pragma unroll
        for (int kw = 0; kw < 3; ++kw)
          wv[kw] = *(const float4*)&s_w[c][kh * 3 + kw][coq << 2];
#pragma unroll
        for (int kw = 0; kw < 3; ++kw) {
#pragma unroll
          for (int wi = 0; wi < 4; ++wi) {
            float iv = in6[wi + kw];
            acc[0][wi] = fmaf(wv[kw].x, iv, acc[0][wi]);
            acc[1][wi] = fmaf(wv[kw].y, iv, acc[1][wi]);
            acc[2][wi] = fmaf(wv[kw].z, iv, acc[2][wi]);
            acc[3][wi] = fmaf(wv[kw].w, iv, acc[3][wi]);
          }
        }
      }
    }
    __syncthreads();
  }

  const int hh = h0 + r;
  if (hh >= H) return;
  const size_t HW = (size_t)H * W;
#pragma unroll
  for (int q = 0; q < 4; ++q) {
    int co = cb + (coq << 2) + q;
    if (co >= Cout) continue;
    float bv = bias[co];
#pragma unroll
    for (int wi = 0; wi < 4; ++wi) {
      int ww = w0 + cg + wi;
      if (ww >= W) continue;
      float v = acc[q][wi] + bv;
      if (mode == MODE_RELU) {
        y[((size_t)n * Cout + co) * HW + (size_t)hh * W + ww] = fmaxf(v, 0.f);
      } else {
        size_t o = ((size_t)n * HW + (size_t)hh * W + ww) * Cout + co;
        y[o] = (mode == MODE_SIG) ? (1.f / (1.f + expf(-v))) : v;
      }
    }
  }
}

// ---------------- top-k: 2-level radix select on positive-float bits ----------------
__global__ __launch_bounds__(256)
void hist_coarse_k(const float* __restrict__ P, int M, unsigned* __restrict__ histC)
{
  __shared__ unsigned lh[4096];
  for (int i = threadIdx.x; i < 4096; i += 256) lh[i] = 0;
  __syncthreads();
  const int n = blockIdx.y;
  const float* p = P + (size_t)n * M;
  for (int i = blockIdx.x * 256 + threadIdx.x; i < M; i += gridDim.x * 256) {
    unsigned b = __float_as_uint(p[i]) >> 18;
    atomicAdd(&lh[b & 4095u], 1u);
  }
  __syncthreads();
  unsigned* h = histC + (size_t)n * 4096;
  for (int i = threadIdx.x; i < 4096; i += 256) {
    unsigned c = lh[i];
    if (c) atomicAdd(&h[i], c);
  }
}

__global__ __launch_bounds__(256)
void hist_fine_k(const float* __restrict__ P, int M, const unsigned* __restrict__ sel,
                 unsigned* __restrict__ histF)
{
  const int n = blockIdx.y;
  const unsigned cb = sel[n * 8 + 0];
  const float* p = P + (size_t)n * M;
  unsigned* h = histF + (size_t)n * 262144;
  for (int i = blockIdx.x * 256 + threadIdx.x; i < M; i += gridDim.x * 256) {
    unsigned b = __float_as_uint(p[i]);
    if ((b >> 18) == cb) atomicAdd(&h[b & 0x3FFFFu], 1u);
  }
}

// find bin where descending cumulative count crosses k
__global__ __launch_bounds__(256)
void radix_scan_k(const unsigned* __restrict__ hist, int nbins,
                  unsigned* __restrict__ sel, int k, int phase)
{
  const int n = blockIdx.x;
  const unsigned* h = hist + (size_t)n * nbins;
  unsigned* s = sel + n * 8;
  const int per = nbins / 256;
  const int tid = threadIdx.x;
  unsigned local = 0;
  for (int i = 0; i < per; ++i) local += h[tid * per + i];
  __shared__ unsigned part[256];
  part[tid] = local;
  __syncthreads();
  unsigned above = 0;
  for (int t = tid + 1; t < 256; ++t) above += part[t];
  unsigned kk = (phase == 0) ? (unsigned)k : ((unsigned)k - s[1]);
  if (above < kk && above + local >= kk) {
    unsigned cum = above;
    for (int i = per - 1; i >= 0; --i) {
      unsigned c = h[tid * per + i];
      if (cum + c >= kk) {
        if (phase == 0) { s[0] = (unsigned)(tid * per + i); s[1] = cum; }
        else { s[2] = (s[0] << 18) | (unsigned)(tid * per + i); s[4] = kk - cum; }
        break;
      }
      cum += c;
    }
  }
}

__global__ __launch_bounds__(256)
void compact_k(const float* __restrict__ P, int M, unsigned* __restrict__ sel,
               float* __restrict__ cv, unsigned* __restrict__ ci, unsigned* __restrict__ eq)
{
  const int n = blockIdx.y;
  unsigned* s = sel + n * 8;
  const unsigned thr = s[2];
  const float* p = P + (size_t)n * M;
  float* cvn = cv + (size_t)n * 1024;
  unsigned* cin_ = ci + (size_t)n * 1024;
  unsigned* eqn = eq + (size_t)n * 8192;
  for (int i = blockIdx.x * 256 + threadIdx.x; i < M; i += gridDim.x * 256) {
    unsigned b = __float_as_uint(p[i]);
    if (b > thr) {
      unsigned g = atomicAdd(&s[5], 1u);
      if (g < 1024u) { cvn[g] = p[i]; cin_[g] = (unsigned)i; }
    } else if (b == thr) {
      unsigned e = atomicAdd(&s[6], 1u);
      if (e < 8192u) eqn[e] = (unsigned)i;
    }
  }
}

// sort candidates desc by (value, then index asc), decode, clip, threshold, emit
__global__ __launch_bounds__(1024)
void finalize_k(const float* __restrict__ cv, const unsigned* __restrict__ ci,
                const unsigned* __restrict__ eq, const unsigned* __restrict__ sel,
                const float* __restrict__ R, const float* __restrict__ anc,
                int k, int lvlOff, int HWA,
                float* __restrict__ candB, float* __restrict__ candS, float* __restrict__ candC)
{
  const int n = blockIdx.x;
  const int tid = threadIdx.x;
  const unsigned* s = sel + n * 8;
  __shared__ float svals[1024];
  __shared__ unsigned sidx[1024];
  __shared__ unsigned long long key[1024];
  const unsigned cntG = s[5] < 1024u ? s[5] : 1024u;
  const unsigned nEq = s[4];
  if (tid < (int)cntG) {
    svals[tid] = cv[(size_t)n * 1024 + tid];
    sidx[tid] = ci[(size_t)n * 1024 + tid];
  }
  __syncthreads();
  if (tid == 0) {
    // append ties at the threshold value, lowest indices first (jax top_k stability)
    unsigned cnt = s[6] < 8192u ? s[6] : 8192u;
    unsigned last = 0; int first = 1;
    float tv = __uint_as_float(s[2]);
    for (unsigned e2 = 0; e2 < nEq && cntG + e2 < 1024u; ++e2) {
      unsigned best = 0xFFFFFFFFu;
      for (unsigned q = 0; q < cnt; ++q) {
        unsigned v = eq[(size_t)n * 8192 + q];
        if ((first || v > last) && v < best) best = v;
      }
      svals[cntG + e2] = tv; sidx[cntG + e2] = best;
      last = best; first = 0;
    }
  }
  __syncthreads();
  const int kk = (int)cntG + (int)nEq;
  key[tid] = (tid < kk)
      ? (((unsigned long long)__float_as_uint(svals[tid]) << 32) |
         (unsigned long long)(0xFFFFFFFFu - sidx[tid]))
      : 0ULL;
  __syncthreads();
  // bitonic sort, descending, 1024 elements
  for (int sz = 2; sz <= 1024; sz <<= 1) {
    for (int st = sz >> 1; st > 0; st >>= 1) {
      int ixj = tid ^ st;
      if (ixj > tid) {
        unsigned long long a = key[tid], b = key[ixj];
        bool up = ((tid & sz) == 0);
        bool sw = up ? (a < b) : (a > b);
        if (sw) { key[tid] = b; key[ixj] = a; }
      }
      __syncthreads();
    }
  }
  if (tid < kk && tid < k) {
    unsigned long long kv = key[tid];
    float val = __uint_as_float((unsigned)(kv >> 32));
    unsigned idx = 0xFFFFFFFFu - (unsigned)(kv & 0xFFFFFFFFu);
    unsigned a = idx / 80u;
    unsigned cls = idx - a * 80u;
    const float* rg = R + ((size_t)n * HWA + a) * 4;
    float a0 = anc[(size_t)a * 4 + 0], a1 = anc[(size_t)a * 4 + 1];
    float a2 = anc[(size_t)a * 4 + 2], a3 = anc[(size_t)a * 4 + 3];
    float wa = a2 - a0, ha = a3 - a1;
    float xa = a0 + 0.5f * wa, ya = a1 + 0.5f * ha;
    float dx = rg[0], dy = rg[1];
    float dw = fminf(rg[2], SCALE_CLAMP_F), dh = fminf(rg[3], SCALE_CLAMP_F);
    float cx = dx * wa + xa, cy = dy * ha + ya;
    float wb = expf(dw) * wa, hb = expf(dh) * ha;
    float x0 = cx - 0.5f * wb, y0 = cy - 0.5f * hb;
    float x1 = cx + 0.5f * wb, y1 = cy + 0.5f * hb;
    x0 = fminf(fmaxf(x0, 0.f), IMG_W_F);
    y0 = fminf(fmaxf(y0, 0.f), IMG_H_F);
    x1 = fminf(fmaxf(x1, 0.f), IMG_W_F);
    y1 = fminf(fmaxf(y1, 0.f), IMG_H_F);
    int o = n * NCAND + lvlOff + tid;
    candB[(size_t)o * 4 + 0] = x0; candB[(size_t)o * 4 + 1] = y0;
    candB[(size_t)o * 4 + 2] = x1; candB[(size_t)o * 4 + 3] = y1;
    candS[o] = (val > SCORE_THR) ? val : 0.f;
    candC[o] = (float)cls;
  }
}

// ---------------- class-aware NMS, one block per image ----------------
__global__ __launch_bounds__(1024)
void nms_k(const float* __restrict__ cB, const float* __restrict__ cS,
           const float* __restrict__ cC, float* __restrict__ out)
{
  const int n = blockIdx.x;
  const int tid = threadIdx.x;
  __shared__ float S[NCAND];
  __shared__ float rv[1024];
  __shared__ int   ri[1024];
  __shared__ float bj[4];
  for (int i = tid; i < NCAND; i += 1024) S[i] = cS[n * NCAND + i];
  __syncthreads();
  for (int it = 0; it < MAXDET; ++it) {
    // argmax with lowest-index tie-break (jnp.argmax semantics)
    float bv = -1.f; int bix = 0;
    for (int i = tid; i < NCAND; i += 1024) {
      float v = S[i];
      if (v > bv) { bv = v; bix = i; }
    }
    rv[tid] = bv; ri[tid] = bix;
    __syncthreads();
    for (int st = 512; st > 0; st >>= 1) {
      if (tid < st) {
        float v2 = rv[tid + st]; int i2 = ri[tid + st];
        if (v2 > rv[tid] || (v2 == rv[tid] && i2 < ri[tid])) { rv[tid] = v2; ri[tid] = i2; }
      }
      __syncthreads();
    }
    const int j = ri[0];
    const float mv = rv[0];
    if (mv <= 0.f) {
      // all remaining scores are zero -> argmax is index 0 forever
      float b0 = cB[(size_t)(n * NCAND) * 4 + 0], b1 = cB[(size_t)(n * NCAND) * 4 + 1];
      float b2 = cB[(size_t)(n * NCAND) * 4 + 2], b3 = cB[(size_t)(n * NCAND) * 4 + 3];
      float c0 = cC[n * NCAND];
      for (int t2 = it + tid; t2 < MAXDET; t2 += 1024) {
        out[((size_t)n * MAXDET + t2) * 4 + 0] = b0;
        out[((size_t)n * MAXDET + t2) * 4 + 1] = b1;
        out[((size_t)n * MAXDET + t2) * 4 + 2] = b2;
        out[((size_t)n * MAXDET + t2) * 4 + 3] = b3;
        out[800 + n * MAXDET + t2] = 0.f;
        out[1000 + n * MAXDET + t2] = c0;
      }
      return;
    }
    if (tid == 0) {
      out[((size_t)n * MAXDET + it) * 4 + 0] = cB[(size_t)(n * NCAND + j) * 4 + 0];
      out[((size_t)n * MAXDET + it) * 4 + 1] = cB[(size_t)(n * NCAND + j) * 4 + 1];
      out[((size_t)n * MAXDET + it) * 4 + 2] = cB[(size_t)(n * NCAND + j) * 4 + 2];
      out[((size_t)n * MAXDET + it) * 4 + 3] = cB[(size_t)(n * NCAND + j) * 4 + 3];
      out[800 + n * MAXDET + it] = mv;
      out[1000 + n * MAXDET + it] = cC[n * NCAND + j];
      float off = cC[n * NCAND + j] * 4096.f;
      bj[0] = cB[(size_t)(n * NCAND + j) * 4 + 0] + off;
      bj[1] = cB[(size_t)(n * NCAND + j) * 4 + 1] + off;
      bj[2] = cB[(size_t)(n * NCAND + j) * 4 + 2] + off;
      bj[3] = cB[(size_t)(n * NCAND + j) * 4 + 3] + off;
    }
    __syncthreads();
    const float jx0 = bj[0], jy0 = bj[1], jx1 = bj[2], jy1 = bj[3];
    const float aj = (jx1 - jx0) * (jy1 - jy0);
    for (int i = tid; i < NCAND; i += 1024) {
      if (S[i] == 0.f) continue;  // zeros stay zero under where(iou>th,0,sc)
      float off = cC[n * NCAND + i] * 4096.f;
      float x0 = cB[(size_t)(n * NCAND + i) * 4 + 0] + off;
      float y0 = cB[(size_t)(n * NCAND + i) * 4 + 1] + off;
      float x1 = cB[(size_t)(n * NCAND + i) * 4 + 2] + off;
      float y1 = cB[(size_t)(n * NCAND + i) * 4 + 3] + off;
      float lx = fmaxf(jx0, x0), ly = fmaxf(jy0, y0);
      float rx = fminf(jx1, x1), ry = fminf(jy1, y1);
      float iw = fmaxf(rx - lx, 0.f), ih = fmaxf(ry - ly, 0.f);
      float inter = iw * ih;
      float ai = (x1 - x0) * (y1 - y0);
      float iou = inter / (aj + ai - inter + 1e-9f);
      if (iou > NMS_THR) S[i] = 0.f;
    }
    if (tid == 0) S[j] = 0.f;
    __syncthreads();
  }
}

// ---------------- host ----------------
extern "C" void kernel_launch(void* const* d_in, const int* in_sizes, int n_in,
                              void* d_out, int out_size, void* d_ws, size_t ws_size,
                              hipStream_t stream)
{
  static const int LH[5]   = {100, 50, 25, 13, 7};
  static const int LW[5]   = {152, 76, 38, 19, 10};
  static const int NTK[5]  = {1000, 1000, 1000, 1000, 630};
  static const int OFFS[5] = {0, 1000, 2000, 3000, 4000};

  const float* feat[5]; const float* anc[5];
  for (int l = 0; l < 5; ++l) {
    feat[l] = (const float*)d_in[l];
    anc[l]  = (const float*)d_in[13 + l];
  }
  const float* csw = (const float*)d_in[5];
  const float* csb = (const float*)d_in[6];
  const float* bsw = (const float*)d_in[7];
  const float* bsb = (const float*)d_in[8];
  const float* scw = (const float*)d_in[9];
  const float* scb = (const float*)d_in[10];
  const float* bpw = (const float*)d_in[11];
  const float* bpb = (const float*)d_in[12];

  float* ws = (float*)d_ws;
  size_t o = 0;
  float* A  = ws + o; o += 7782400;            // ping  (2*256*100*152)
  float* Bb = ws + o; o += 7782400;            // pong
  float* P  = ws + o; o += 21888000;           // probs NHWC720 (2*15200*720)
  float* R  = ws + o; o += 1094400;            // reg NHWC36 (2*136800*4... = 2*15200*36)
  float* candB = ws + o; o += (size_t)NIMG * NCAND * 4;
  float* candS = ws + o; o += NIMG * NCAND;
  float* candC = ws + o; o += NIMG * NCAND;
  float* candV = ws + o; o += NIMG * 1024;
  unsigned* candI = (unsigned*)(ws + o); o += NIMG * 1024;
  unsigned* eqI   = (unsigned*)(ws + o); o += NIMG * 8192;
  unsigned* histC = (unsigned*)(ws + o); o += NIMG * 4096;
  unsigned* histF = (unsigned*)(ws + o); o += NIMG * 262144;
  unsigned* sel   = (unsigned*)(ws + o); o += NIMG * 8;
  if (ws_size < o * sizeof(float)) return;  // ~157 MB required

  float* out = (float*)d_out;

  for (int l = 0; l < 5; ++l) {
    const int H = LH[l], W = LW[l];
    const int HW = H * W;
    const int HWA = HW * 9;
    const int M = HW * 720;
    const int k = NTK[l];
    auto conv = [&](const float* xin, const float* wgt, const float* bia, float* yo,
                    int Cout, int mode) {
      dim3 grd((W + TW - 1) / TW, (H + TH - 1) / TH, NIMG * ((Cout + COT - 1) / COT));
      conv3x3_k<<<grd, dim3(256), 0, stream>>>(xin, wgt, bia, yo, H, W, Cout, mode);
    };
    // cls tower + cls head (-> sigmoid probs, reference flatten order)
    conv(feat[l], csw + (size_t)0 * 589824, csb + 0,   A,  256, MODE_RELU);
    conv(A,       csw + (size_t)1 * 589824, csb + 256, Bb, 256, MODE_RELU);
    conv(Bb,      csw + (size_t)2 * 589824, csb + 512, A,  256, MODE_RELU);
    conv(A,       csw + (size_t)3 * 589824, csb + 768, Bb, 256, MODE_RELU);
    conv(Bb, scw, scb, P, 720, MODE_SIG);
    // bbox tower + bbox head
    conv(feat[l], bsw + (size_t)0 * 589824, bsb + 0,   A,  256, MODE_RELU);
    conv(A,       bsw + (size_t)1 * 589824, bsb + 256, Bb, 256, MODE_RELU);
    conv(Bb,      bsw + (size_t)2 * 589824, bsb + 512, A,  256, MODE_RELU);
    conv(A,       bsw + (size_t)3 * 589824, bsb + 768, Bb, 256, MODE_RELU);
    conv(Bb, bpw, bpb, R, 36, MODE_RAW);

    // top-k select + decode
    hipMemsetAsync(histC, 0, NIMG * 4096 * sizeof(unsigned), stream);
    hipMemsetAsync(histF, 0, NIMG * 262144 * sizeof(unsigned), stream);
    hipMemsetAsync(sel,   0, NIMG * 8 * sizeof(unsigned), stream);
    hist_coarse_k<<<dim3(256, NIMG), dim3(256), 0, stream>>>(P, M, histC);
    radix_scan_k<<<dim3(NIMG), dim3(256), 0, stream>>>(histC, 4096, sel, k, 0);
    hist_fine_k<<<dim3(256, NIMG), dim3(256), 0, stream>>>(P, M, sel, histF);
    radix_scan_k<<<dim3(NIMG), dim3(256), 0, stream>>>(histF, 262144, sel, k, 1);
    compact_k<<<dim3(256, NIMG), dim3(256), 0, stream>>>(P, M, sel, candV, candI, eqI);
    finalize_k<<<dim3(NIMG), dim3(1024), 0, stream>>>(candV, candI, eqI, sel, R, anc[l],
                                                      k, OFFS[l], HWA, candB, candS, candC);
  }
  nms_k<<<dim3(NIMG), dim3(1024), 0, stream>>>(candB, candS, candC, out);
}

// Round 3
// 6652.352 us; speedup vs baseline: 3.1764x; 3.1764x over previous
//
#include <hip/hip_runtime.h>
#include <math.h>

#define NIMG 2
#define NCAND 4630
#define MAXDET 100
#define IMG_W_F 1216.0f
#define IMG_H_F 800.0f
#define SCORE_THR 0.05f
#define NMS_THR 0.5f
#define SCALE_CLAMP_F 4.135166556742356f  // log(1000/16)

typedef __attribute__((ext_vector_type(8))) short short8v;
typedef __attribute__((ext_vector_type(8))) unsigned short u16x8;
typedef __attribute__((ext_vector_type(16))) float f32x16;

__device__ __forceinline__ unsigned short f2bf(float f) {
  unsigned u = __float_as_uint(f);
  u += 0x7FFFu + ((u >> 16) & 1u);
  return (unsigned short)(u >> 16);
}
__device__ __forceinline__ float bf2f(unsigned short h) {
  return __uint_as_float(((unsigned)h) << 16);
}

// ---------------------------------------------------------------------------
// Weight prepack: OIHW fp32 -> [plane][tap][cb16][coF][lane64][8] bf16 frags
// frag layout matches mfma_f32_32x32x16_bf16 B operand:
//   lane l holds B[k=(l>>5)*8+j][co=l&31]
// ---------------------------------------------------------------------------
__global__ __launch_bounds__(256)
void prepack_k(const float* __restrict__ src, unsigned short* __restrict__ dst,
               int Cout, int nCoF, int planes)
{
  const int total = 9 * 16 * nCoF * 64;
  int t = blockIdx.x * 256 + threadIdx.x;
  if (t >= total) return;
  const int l = t & 63;
  const int rest = t >> 6;             // (tap*16+cb)*nCoF + coF
  const int coF = rest % nCoF;
  const int tc = rest / nCoF;
  const int tap = tc >> 4;
  const int cb = tc & 15;
  const int co = coF * 32 + (l & 31);
  const int ciB = cb * 16 + (l >> 5) * 8;
  const unsigned planeStride = 9u * 16u * (unsigned)nCoF * 512u;
#pragma unroll
  for (int j = 0; j < 8; ++j) {
    float v = 0.f;
    if (co < Cout) v = src[(size_t)(co * 256 + ciB + j) * 9 + tap];
    unsigned short hi = f2bf(v);
    dst[(size_t)t * 8 + j] = hi;
    if (planes == 2) dst[planeStride + (size_t)t * 8 + j] = f2bf(v - bf2f(hi));
  }
}

// ---------------------------------------------------------------------------
// feat fp32 NCHW -> padded NC16HW16 bf16 hi/lo planes
// layout: [cb16][plane][n][hp][wp][16ci], halo assumed pre-zeroed
// ---------------------------------------------------------------------------
__global__ __launch_bounds__(256)
void convert_k(const float* __restrict__ x, unsigned short* __restrict__ act,
               int H, int W)
{
  const int h = blockIdx.x, n = blockIdx.y;
  const int Hp = H + 2, Wp = W + 2, HpWp = Hp * Wp;
  const unsigned PSu = 2u * (unsigned)HpWp * 16u;  // per-plane ushorts (N=2)
  __shared__ float s[64][154];
  for (int c0 = 0; c0 < 256; c0 += 64) {
    for (int idx = threadIdx.x; idx < 64 * W; idx += 256) {
      int c = idx / W, w = idx - c * W;
      s[c][w] = x[((size_t)(n * 256 + c0 + c) * H + h) * W + w];
    }
    __syncthreads();
    for (int idx = threadIdx.x; idx < 4 * W; idx += 256) {
      int ch = idx / W, w = idx - ch * W;
      int cchunk = (c0 >> 4) + ch;
      unsigned base = (unsigned)cchunk * 2u * PSu +
                      ((unsigned)((n * Hp + h + 1) * Wp + (w + 1))) * 16u;
      u16x8 hv0, hv1, lv0, lv1;
#pragma unroll
      for (int j = 0; j < 8; ++j) {
        float f0 = s[ch * 16 + j][w];
        float f1 = s[ch * 16 + 8 + j][w];
        unsigned short h0 = f2bf(f0), h1 = f2bf(f1);
        hv0[j] = h0; hv1[j] = h1;
        lv0[j] = f2bf(f0 - bf2f(h0));
        lv1[j] = f2bf(f1 - bf2f(h1));
      }
      *(u16x8*)(act + base) = hv0;
      *(u16x8*)(act + base + 8) = hv1;
      *(u16x8*)(act + base + PSu) = lv0;
      *(u16x8*)(act + base + PSu + 8) = lv1;
    }
    __syncthreads();
  }
}

// ---------------------------------------------------------------------------
// Implicit-GEMM conv3x3 via mfma_f32_32x32x16_bf16.
// SPLIT=1: bf16x2 error-compensated (3 mfma per logical product).
// MODE: 0 = tower (relu, write padded act hi[/lo]); 1 = cls head (sigmoid->P
//        per-image, m_local*720+co); 2 = bbox head (raw->R, m_global*36+co)
// One wave per block; wave tile 64(M) x 64(CO): 4 accumulators.
// ---------------------------------------------------------------------------
template<int SPLIT, int MODE>
__global__ __launch_bounds__(64)
void conv_mfma_k(const unsigned short* __restrict__ actIn,
                 const unsigned short* __restrict__ wpk,
                 const float* __restrict__ bias,
                 unsigned short* __restrict__ actOut,
                 float* __restrict__ headOut,
                 int H, int W, int Cout, int nCoF, int mBase, int Mloc)
{
  const int Wp = W + 2;
  const int HW = H * W;
  const int HpWp = (H + 2) * Wp;
  const unsigned PSu = 2u * (unsigned)HpWp * 16u;
  const unsigned WPL = 9u * 16u * (unsigned)nCoF * 512u;

  const int l = threadIdx.x;
  const int lw = l & 31;
  const int lh = l >> 5;

  unsigned V[2];
#pragma unroll
  for (int i = 0; i < 2; ++i) {
    int mloc = blockIdx.x * 64 + i * 32 + lw;
    if (mloc >= Mloc) mloc = Mloc - 1;
    int mg = mBase + mloc;
    int n = mg / HW; int rem = mg - n * HW;
    int h = rem / W; int w = rem - h * W;
    V[i] = ((unsigned)(n * HpWp + h * Wp + w)) * 16u + (unsigned)lh * 8u;
  }

  unsigned tOffA[9];
#pragma unroll
  for (int t = 0; t < 9; ++t)
    tOffA[t] = ((unsigned)((t / 3) * Wp + (t % 3))) * 16u;

  const int coF0 = blockIdx.y * 2;
  const unsigned lOff = (unsigned)l * 8u;

  f32x16 acc00 = {}, acc01 = {}, acc10 = {}, acc11 = {};

  for (int cb = 0; cb < 16; ++cb) {
    const unsigned short* aH = actIn + (unsigned)cb * 2u * PSu;
    const unsigned short* aL = aH + PSu;
    const unsigned short* wB = wpk + ((unsigned)cb * (unsigned)nCoF + (unsigned)coF0) * 512u;
#pragma unroll
    for (int tap = 0; tap < 9; ++tap) {
      const unsigned to = tOffA[tap];
      const unsigned short* wT = wB + (unsigned)tap * 16u * (unsigned)nCoF * 512u;
      short8v a0h = *(const short8v*)(aH + to + V[0]);
      short8v a1h = *(const short8v*)(aH + to + V[1]);
      short8v b0h = *(const short8v*)(wT + lOff);
      short8v b1h = *(const short8v*)(wT + 512u + lOff);
      acc00 = __builtin_amdgcn_mfma_f32_32x32x16_bf16(a0h, b0h, acc00, 0, 0, 0);
      acc01 = __builtin_amdgcn_mfma_f32_32x32x16_bf16(a0h, b1h, acc01, 0, 0, 0);
      acc10 = __builtin_amdgcn_mfma_f32_32x32x16_bf16(a1h, b0h, acc10, 0, 0, 0);
      acc11 = __builtin_amdgcn_mfma_f32_32x32x16_bf16(a1h, b1h, acc11, 0, 0, 0);
      if (SPLIT) {
        short8v a0l = *(const short8v*)(aL + to + V[0]);
        short8v a1l = *(const short8v*)(aL + to + V[1]);
        short8v b0l = *(const short8v*)(wT + WPL + lOff);
        short8v b1l = *(const short8v*)(wT + WPL + 512u + lOff);
        acc00 = __builtin_amdgcn_mfma_f32_32x32x16_bf16(a0h, b0l, acc00, 0, 0, 0);
        acc01 = __builtin_amdgcn_mfma_f32_32x32x16_bf16(a0h, b1l, acc01, 0, 0, 0);
        acc10 = __builtin_amdgcn_mfma_f32_32x32x16_bf16(a1h, b0l, acc10, 0, 0, 0);
        acc11 = __builtin_amdgcn_mfma_f32_32x32x16_bf16(a1h, b1l, acc11, 0, 0, 0);
        acc00 = __builtin_amdgcn_mfma_f32_32x32x16_bf16(a0l, b0h, acc00, 0, 0, 0);
        acc01 = __builtin_amdgcn_mfma_f32_32x32x16_bf16(a0l, b1h, acc01, 0, 0, 0);
        acc10 = __builtin_amdgcn_mfma_f32_32x32x16_bf16(a1l, b0h, acc10, 0, 0, 0);
        acc11 = __builtin_amdgcn_mfma_f32_32x32x16_bf16(a1l, b1h, acc11, 0, 0, 0);
      }
    }
  }

  const int coBase = blockIdx.y * 64;
  auto emit = [&](const f32x16& A, int i, int f) {
    const int co = coBase + f * 32 + lw;
    const float bv = (co < Cout) ? bias[co] : 0.f;
#pragma unroll
    for (int r = 0; r < 16; ++r) {
      int mloc = blockIdx.x * 64 + i * 32 + ((r & 3) + 8 * (r >> 2) + 4 * lh);
      if (mloc >= Mloc) continue;
      float v = A[r] + bv;
      if (MODE == 0) {
        if (co < Cout) {
          v = fmaxf(v, 0.f);
          int mg = mBase + mloc;
          int n = mg / HW; int rem = mg - n * HW;
          int h = rem / W; int w = rem - h * W;
          unsigned addr = ((unsigned)(co >> 4)) * 2u * PSu +
                          ((unsigned)(n * HpWp + (h + 1) * Wp + (w + 1))) * 16u +
                          (unsigned)(co & 15);
          unsigned short hi = f2bf(v);
          actOut[addr] = hi;
          if (SPLIT) actOut[addr + PSu] = f2bf(v - bf2f(hi));
        }
      } else if (MODE == 1) {
        if (co < 720) headOut[(size_t)mloc * 720 + co] = 1.f / (1.f + expf(-v));
      } else {
        if (co < 36) headOut[(size_t)(mBase + mloc) * 36 + co] = v;
      }
    }
  };
  emit(acc00, 0, 0); emit(acc01, 0, 1); emit(acc10, 1, 0); emit(acc11, 1, 1);
}

// ---------------- top-k: 2-level radix select (per image) ----------------
__global__ __launch_bounds__(256)
void hist_coarse_k(const float* __restrict__ P, int M, unsigned* __restrict__ histC)
{
  __shared__ unsigned lh[4096];
  for (int i = threadIdx.x; i < 4096; i += 256) lh[i] = 0;
  __syncthreads();
  for (int i = blockIdx.x * 256 + threadIdx.x; i < M; i += gridDim.x * 256) {
    unsigned b = __float_as_uint(P[i]) >> 18;
    atomicAdd(&lh[b & 4095u], 1u);
  }
  __syncthreads();
  for (int i = threadIdx.x; i < 4096; i += 256) {
    unsigned c = lh[i];
    if (c) atomicAdd(&histC[i], c);
  }
}

__global__ __launch_bounds__(256)
void hist_fine_k(const float* __restrict__ P, int M, const unsigned* __restrict__ sel,
                 unsigned* __restrict__ histF)
{
  const unsigned cb = sel[0];
  for (int i = blockIdx.x * 256 + threadIdx.x; i < M; i += gridDim.x * 256) {
    unsigned b = __float_as_uint(P[i]);
    if ((b >> 18) == cb) atomicAdd(&histF[b & 0x3FFFFu], 1u);
  }
}

__global__ __launch_bounds__(1024)
void radix_scan_k(const unsigned* __restrict__ hist, int nbins,
                  unsigned* __restrict__ s, int k, int phase)
{
  const int per = nbins / 1024;
  const int tid = threadIdx.x;
  unsigned local = 0;
  for (int i = 0; i < per; ++i) local += hist[tid * per + i];
  __shared__ unsigned part[1024];
  part[tid] = local;
  __syncthreads();
  unsigned above = 0;
  for (int t = tid + 1; t < 1024; ++t) above += part[t];
  unsigned kk = (phase == 0) ? (unsigned)k : ((unsigned)k - s[1]);
  if (above < kk && above + local >= kk) {
    unsigned cum = above;
    for (int i = per - 1; i >= 0; --i) {
      unsigned c = hist[tid * per + i];
      if (cum + c >= kk) {
        if (phase == 0) { s[0] = (unsigned)(tid * per + i); s[1] = cum; }
        else { s[2] = (s[0] << 18) | (unsigned)(tid * per + i); s[4] = kk - cum; }
        break;
      }
      cum += c;
    }
  }
}

__global__ __launch_bounds__(256)
void compact_k(const float* __restrict__ P, int M, unsigned* __restrict__ s,
               float* __restrict__ cv, unsigned* __restrict__ ci, unsigned* __restrict__ eq)
{
  const unsigned thr = s[2];
  for (int i = blockIdx.x * 256 + threadIdx.x; i < M; i += gridDim.x * 256) {
    unsigned b = __float_as_uint(P[i]);
    if (b > thr) {
      unsigned g = atomicAdd(&s[5], 1u);
      if (g < 1024u) { cv[g] = P[i]; ci[g] = (unsigned)i; }
    } else if (b == thr) {
      unsigned e = atomicAdd(&s[6], 1u);
      if (e < 8192u) eq[e] = (unsigned)i;
    }
  }
}

__global__ __launch_bounds__(1024)
void finalize_k(const float* __restrict__ cv, const unsigned* __restrict__ ci,
                const unsigned* __restrict__ eq, const unsigned* __restrict__ s,
                const float* __restrict__ R, const float* __restrict__ anc,
                int k, int outBase, int HWA, int n,
                float* __restrict__ candB, float* __restrict__ candS, float* __restrict__ candC)
{
  const int tid = threadIdx.x;
  __shared__ float svals[1024];
  __shared__ unsigned sidx[1024];
  __shared__ unsigned long long key[1024];
  const unsigned cntG = s[5] < 1024u ? s[5] : 1024u;
  const unsigned nEq = s[4];
  if (tid < (int)cntG) { svals[tid] = cv[tid]; sidx[tid] = ci[tid]; }
  __syncthreads();
  if (tid == 0) {
    unsigned cnt = s[6] < 8192u ? s[6] : 8192u;
    unsigned last = 0; int first = 1;
    float tv = __uint_as_float(s[2]);
    for (unsigned e2 = 0; e2 < nEq && cntG + e2 < 1024u; ++e2) {
      unsigned best = 0xFFFFFFFFu;
      for (unsigned q = 0; q < cnt; ++q) {
        unsigned v = eq[q];
        if ((first || v > last) && v < best) best = v;
      }
      svals[cntG + e2] = tv; sidx[cntG + e2] = best;
      last = best; first = 0;
    }
  }
  __syncthreads();
  const int kk = (int)cntG + (int)nEq;
  key[tid] = (tid < kk)
      ? (((unsigned long long)__float_as_uint(svals[tid]) << 32) |
         (unsigned long long)(0xFFFFFFFFu - sidx[tid]))
      : 0ULL;
  __syncthreads();
  for (int sz = 2; sz <= 1024; sz <<= 1) {
    for (int st = sz >> 1; st > 0; st >>= 1) {
      int ixj = tid ^ st;
      if (ixj > tid) {
        unsigned long long a = key[tid], b = key[ixj];
        bool up = ((tid & sz) == 0);
        if (up ? (a < b) : (a > b)) { key[tid] = b; key[ixj] = a; }
      }
      __syncthreads();
    }
  }
  if (tid < kk && tid < k) {
    unsigned long long kv = key[tid];
    float val = __uint_as_float((unsigned)(kv >> 32));
    unsigned idx = 0xFFFFFFFFu - (unsigned)(kv & 0xFFFFFFFFu);
    unsigned a = idx / 80u;
    unsigned cls = idx - a * 80u;
    const float* rg = R + ((size_t)n * HWA + a) * 4;
    float a0 = anc[(size_t)a * 4 + 0], a1 = anc[(size_t)a * 4 + 1];
    float a2 = anc[(size_t)a * 4 + 2], a3 = anc[(size_t)a * 4 + 3];
    float wa = a2 - a0, ha = a3 - a1;
    float xa = a0 + 0.5f * wa, ya = a1 + 0.5f * ha;
    float dx = rg[0], dy = rg[1];
    float dw = fminf(rg[2], SCALE_CLAMP_F), dh = fminf(rg[3], SCALE_CLAMP_F);
    float cx = dx * wa + xa, cy = dy * ha + ya;
    float wb = expf(dw) * wa, hb = expf(dh) * ha;
    float x0 = cx - 0.5f * wb, y0 = cy - 0.5f * hb;
    float x1 = cx + 0.5f * wb, y1 = cy + 0.5f * hb;
    x0 = fminf(fmaxf(x0, 0.f), IMG_W_F);
    y0 = fminf(fmaxf(y0, 0.f), IMG_H_F);
    x1 = fminf(fmaxf(x1, 0.f), IMG_W_F);
    y1 = fminf(fmaxf(y1, 0.f), IMG_H_F);
    int o = outBase + tid;
    candB[(size_t)o * 4 + 0] = x0; candB[(size_t)o * 4 + 1] = y0;
    candB[(size_t)o * 4 + 2] = x1; candB[(size_t)o * 4 + 3] = y1;
    candS[o] = (val > SCORE_THR) ? val : 0.f;
    candC[o] = (float)cls;
  }
}

// ---------------- class-aware NMS, one block per image ----------------
__global__ __launch_bounds__(1024)
void nms_k(const float* __restrict__ cB, const float* __restrict__ cS,
           const float* __restrict__ cC, float* __restrict__ out)
{
  const int n = blockIdx.x;
  const int tid = threadIdx.x;
  __shared__ float S[NCAND];
  __shared__ float rv[1024];
  __shared__ int ri[1024];
  __shared__ float bj[4];
  for (int i = tid; i < NCAND; i += 1024) S[i] = cS[n * NCAND + i];
  __syncthreads();
  for (int it = 0; it < MAXDET; ++it) {
    float bv = -1.f; int bix = 0;
    for (int i = tid; i < NCAND; i += 1024) {
      float v = S[i];
      if (v > bv) { bv = v; bix = i; }
    }
    rv[tid] = bv; ri[tid] = bix;
    __syncthreads();
    for (int st = 512; st > 0; st >>= 1) {
      if (tid < st) {
        float v2 = rv[tid + st]; int i2 = ri[tid + st];
        if (v2 > rv[tid] || (v2 == rv[tid] && i2 < ri[tid])) { rv[tid] = v2; ri[tid] = i2; }
      }
      __syncthreads();
    }
    const int j = ri[0];
    const float mv = rv[0];
    if (mv <= 0.f) {
      float b0 = cB[(size_t)(n * NCAND) * 4 + 0], b1 = cB[(size_t)(n * NCAND) * 4 + 1];
      float b2 = cB[(size_t)(n * NCAND) * 4 + 2], b3 = cB[(size_t)(n * NCAND) * 4 + 3];
      float c0 = cC[n * NCAND];
      for (int t2 = it + tid; t2 < MAXDET; t2 += 1024) {
        out[((size_t)n * MAXDET + t2) * 4 + 0] = b0;
        out[((size_t)n * MAXDET + t2) * 4 + 1] = b1;
        out[((size_t)n * MAXDET + t2) * 4 + 2] = b2;
        out[((size_t)n * MAXDET + t2) * 4 + 3] = b3;
        out[800 + n * MAXDET + t2] = 0.f;
        out[1000 + n * MAXDET + t2] = c0;
      }
      return;
    }
    if (tid == 0) {
      out[((size_t)n * MAXDET + it) * 4 + 0] = cB[(size_t)(n * NCAND + j) * 4 + 0];
      out[((size_t)n * MAXDET + it) * 4 + 1] = cB[(size_t)(n * NCAND + j) * 4 + 1];
      out[((size_t)n * MAXDET + it) * 4 + 2] = cB[(size_t)(n * NCAND + j) * 4 + 2];
      out[((size_t)n * MAXDET + it) * 4 + 3] = cB[(size_t)(n * NCAND + j) * 4 + 3];
      out[800 + n * MAXDET + it] = mv;
      out[1000 + n * MAXDET + it] = cC[n * NCAND + j];
      float off = cC[n * NCAND + j] * 4096.f;
      bj[0] = cB[(size_t)(n * NCAND + j) * 4 + 0] + off;
      bj[1] = cB[(size_t)(n * NCAND + j) * 4 + 1] + off;
      bj[2] = cB[(size_t)(n * NCAND + j) * 4 + 2] + off;
      bj[3] = cB[(size_t)(n * NCAND + j) * 4 + 3] + off;
    }
    __syncthreads();
    const float jx0 = bj[0], jy0 = bj[1], jx1 = bj[2], jy1 = bj[3];
    const float aj = (jx1 - jx0) * (jy1 - jy0);
    for (int i = tid; i < NCAND; i += 1024) {
      if (S[i] == 0.f) continue;
      float off = cC[n * NCAND + i] * 4096.f;
      float x0 = cB[(size_t)(n * NCAND + i) * 4 + 0] + off;
      float y0 = cB[(size_t)(n * NCAND + i) * 4 + 1] + off;
      float x1 = cB[(size_t)(n * NCAND + i) * 4 + 2] + off;
      float y1 = cB[(size_t)(n * NCAND + i) * 4 + 3] + off;
      float lx = fmaxf(jx0, x0), ly = fmaxf(jy0, y0);
      float rx = fminf(jx1, x1), ry = fminf(jy1, y1);
      float iw = fmaxf(rx - lx, 0.f), ih = fmaxf(ry - ly, 0.f);
      float inter = iw * ih;
      float ai = (x1 - x0) * (y1 - y0);
      float iou = inter / (aj + ai - inter + 1e-9f);
      if (iou > NMS_THR) S[i] = 0.f;
    }
    if (tid == 0) S[j] = 0.f;
    __syncthreads();
  }
}

// ---------------- host ----------------
extern "C" void kernel_launch(void* const* d_in, const int* in_sizes, int n_in,
                              void* d_out, int out_size, void* d_ws, size_t ws_size,
                              hipStream_t stream)
{
  static const int LH[5] = {100, 50, 25, 13, 7};
  static const int LW[5] = {152, 76, 38, 19, 10};
  static const int NTK[5] = {1000, 1000, 1000, 1000, 630};
  static const int OFFS[5] = {0, 1000, 2000, 3000, 4000};

  const float* feat[5]; const float* anc[5];
  for (int l = 0; l < 5; ++l) {
    feat[l] = (const float*)d_in[l];
    anc[l] = (const float*)d_in[13 + l];
  }
  const float* csw = (const float*)d_in[5];
  const float* csb = (const float*)d_in[6];
  const float* bsw = (const float*)d_in[7];
  const float* bsb = (const float*)d_in[8];
  const float* scw = (const float*)d_in[9];
  const float* scb = (const float*)d_in[10];
  const float* bpw = (const float*)d_in[11];
  const float* bpb = (const float*)d_in[12];

  float* ws = (float*)d_ws;
  size_t o = 0;
  unsigned short* ping = (unsigned short*)(ws + o); o += 8042496;  // 16,084,992 u16
  unsigned short* pong = (unsigned short*)(ws + o); o += 8042496;
  unsigned short* wpk  = (unsigned short*)(ws + o); o += 5382144;  // 10,764,288 u16
  float* P = ws + o; o += 10944000;                                // per-image probs (L0 size)
  float* R = ws + o; o += 1094400;                                 // both-image deltas (L0)
  float* candB = ws + o; o += (size_t)NIMG * NCAND * 4;
  float* candS = ws + o; o += NIMG * NCAND;
  float* candC = ws + o; o += NIMG * NCAND;
  float* candV = ws + o; o += NIMG * 1024;
  unsigned* candI = (unsigned*)(ws + o); o += NIMG * 1024;
  unsigned* eqI = (unsigned*)(ws + o); o += NIMG * 8192;
  unsigned* histC = (unsigned*)(ws + o); o += NIMG * 4096;
  unsigned* histF = (unsigned*)(ws + o); o += NIMG * 262144;
  unsigned* sel = (unsigned*)(ws + o); o += NIMG * 8;
  if (ws_size < o * sizeof(float)) return;  // ~137 MB required

  float* out = (float*)d_out;

  // --- weight prepack (10 convs) ---
  for (int i = 0; i < 4; ++i) {
    int tot = 9 * 16 * 8 * 64;
    prepack_k<<<dim3((tot + 255) / 256), dim3(256), 0, stream>>>(
        csw + (size_t)i * 589824, wpk + (size_t)i * 1179648, 256, 8, 2);
    prepack_k<<<dim3((tot + 255) / 256), dim3(256), 0, stream>>>(
        bsw + (size_t)i * 589824, wpk + 4718592 + (size_t)i * 589824, 256, 8, 1);
  }
  {
    int tot = 9 * 16 * 24 * 64;
    prepack_k<<<dim3((tot + 255) / 256), dim3(256), 0, stream>>>(
        scw, wpk + 7077888, 720, 24, 2);
    tot = 9 * 16 * 2 * 64;
    prepack_k<<<dim3((tot + 255) / 256), dim3(256), 0, stream>>>(
        bpw, wpk + 10616832, 36, 2, 1);
  }

  for (int l = 0; l < 5; ++l) {
    const int H = LH[l], W = LW[l];
    const int HW = H * W, Hp = H + 2, Wp = W + 2;
    const int HpWp = Hp * Wp;
    const int HWA = HW * 9;
    const int M = HW * 720;
    const int k = NTK[l];
    // 16cb * 2planes * NIMG * 16ci * 2B = 2048 B per padded pixel
    const size_t lvlBytes = (size_t)HpWp * 2048;
    hipMemsetAsync(ping, 0, lvlBytes, stream);
    hipMemsetAsync(pong, 0, lvlBytes, stream);

    const int Mtot = 2 * HW;
    const int gmT = (Mtot + 63) / 64;
    const int gmH = (HW + 63) / 64;

    // cls chain (split bf16x2)
    convert_k<<<dim3(H, NIMG), dim3(256), 0, stream>>>(feat[l], ping, H, W);
    conv_mfma_k<1, 0><<<dim3(gmT, 4), dim3(64), 0, stream>>>(
        ping, wpk + 0 * 1179648, csb + 0, pong, nullptr, H, W, 256, 8, 0, Mtot);
    conv_mfma_k<1, 0><<<dim3(gmT, 4), dim3(64), 0, stream>>>(
        pong, wpk + 1 * 1179648, csb + 256, ping, nullptr, H, W, 256, 8, 0, Mtot);
    conv_mfma_k<1, 0><<<dim3(gmT, 4), dim3(64), 0, stream>>>(
        ping, wpk + 2 * 1179648, csb + 512, pong, nullptr, H, W, 256, 8, 0, Mtot);
    conv_mfma_k<1, 0><<<dim3(gmT, 4), dim3(64), 0, stream>>>(
        pong, wpk + 3 * 1179648, csb + 768, ping, nullptr, H, W, 256, 8, 0, Mtot);
    for (int n = 0; n < NIMG; ++n) {
      conv_mfma_k<1, 1><<<dim3(gmH, 12), dim3(64), 0, stream>>>(
          ping, wpk + 7077888, scb, nullptr, P, H, W, 720, 24, n * HW, HW);
      unsigned* sel_n = sel + n * 8;
      hipMemsetAsync(histC + n * 4096, 0, 4096 * sizeof(unsigned), stream);
      hipMemsetAsync(histF + (size_t)n * 262144, 0, 262144 * sizeof(unsigned), stream);
      hipMemsetAsync(sel_n, 0, 8 * sizeof(unsigned), stream);
      hist_coarse_k<<<dim3(256), dim3(256), 0, stream>>>(P, M, histC + n * 4096);
      radix_scan_k<<<dim3(1), dim3(1024), 0, stream>>>(histC + n * 4096, 4096, sel_n, k, 0);
      hist_fine_k<<<dim3(256), dim3(256), 0, stream>>>(P, M, sel_n, histF + (size_t)n * 262144);
      radix_scan_k<<<dim3(1), dim3(1024), 0, stream>>>(histF + (size_t)n * 262144, 262144, sel_n, k, 1);
      compact_k<<<dim3(256), dim3(256), 0, stream>>>(P, M, sel_n,
          candV + n * 1024, candI + n * 1024, eqI + (size_t)n * 8192);
    }

    // bbox chain (plain bf16)
    convert_k<<<dim3(H, NIMG), dim3(256), 0, stream>>>(feat[l], ping, H, W);
    conv_mfma_k<0, 0><<<dim3(gmT, 4), dim3(64), 0, stream>>>(
        ping, wpk + 4718592 + 0 * 589824, bsb + 0, pong, nullptr, H, W, 256, 8, 0, Mtot);
    conv_mfma_k<0, 0><<<dim3(gmT, 4), dim3(64), 0, stream>>>(
        pong, wpk + 4718592 + 1 * 589824, bsb + 256, ping, nullptr, H, W, 256, 8, 0, Mtot);
    conv_mfma_k<0, 0><<<dim3(gmT, 4), dim3(64), 0, stream>>>(
        ping, wpk + 4718592 + 2 * 589824, bsb + 512, pong, nullptr, H, W, 256, 8, 0, Mtot);
    conv_mfma_k<0, 0><<<dim3(gmT, 4), dim3(64), 0, stream>>>(
        pong, wpk + 4718592 + 3 * 589824, bsb + 768, ping, nullptr, H, W, 256, 8, 0, Mtot);
    conv_mfma_k<0, 2><<<dim3(gmT, 1), dim3(64), 0, stream>>>(
        ping, wpk + 10616832, bpb, nullptr, R, H, W, 36, 2, 0, Mtot);

    for (int n = 0; n < NIMG; ++n) {
      finalize_k<<<dim3(1), dim3(1024), 0, stream>>>(
          candV + n * 1024, candI + n * 1024, eqI + (size_t)n * 8192, sel + n * 8,
          R, anc[l], k, n * NCAND + OFFS[l], HWA, n, candB, candS, candC);
    }
  }
  nms_k<<<dim3(NIMG), dim3(1024), 0, stream>>>(candB, candS, candC, out);
}

// Round 4
// 3997.715 us; speedup vs baseline: 5.2856x; 1.6640x over previous
//
#include <hip/hip_runtime.h>
#include <math.h>

#define NIMG 2
#define NCAND 4630
#define MAXDET 100
#define IMG_W_F 1216.0f
#define IMG_H_F 800.0f
#define SCORE_THR 0.05f
#define NMS_THR 0.5f
#define SCALE_CLAMP_F 4.135166556742356f  // log(1000/16)

typedef __attribute__((ext_vector_type(8))) _Float16 f16x8;
typedef __attribute__((ext_vector_type(16))) float f32x16;

// weight-pack offsets in halfs: [clsT0..3][bbxT0..3][clsHead][bbxHead]
#define WOFF_CLS_T(i) ((unsigned)(i) * 589824u)
#define WOFF_BBX_T(i) (2359296u + (unsigned)(i) * 589824u)
#define WOFF_CLS_H 4718592u
#define WOFF_BBX_H 6488064u
#define WPK_TOTAL 6635520u

// ---------------------------------------------------------------------------
// Weight prepack: OIHW fp32 -> [tap][cb16][coF][lane64][8] f16 frags
// B-frag for mfma_f32_32x32x16_f16: lane l holds B[k=(l>>5)*8+j][co=l&31]
// ---------------------------------------------------------------------------
__global__ __launch_bounds__(256)
void prepack_k(const float* __restrict__ src, _Float16* __restrict__ dst,
               int Cout, int nCoF)
{
  const int total = 9 * 16 * nCoF * 64;
  int t = blockIdx.x * 256 + threadIdx.x;
  if (t >= total) return;
  const int l = t & 63;
  const int rest = t >> 6;             // (tap*16+cb)*nCoF + coF
  const int coF = rest % nCoF;
  const int tc = rest / nCoF;
  const int tap = tc >> 4;
  const int cb = tc & 15;
  const int co = coF * 32 + (l & 31);
  const int ciB = cb * 16 + (l >> 5) * 8;
#pragma unroll
  for (int j = 0; j < 8; ++j) {
    float v = 0.f;
    if (co < Cout) v = src[(size_t)(co * 256 + ciB + j) * 9 + tap];
    dst[(size_t)t * 8 + j] = (_Float16)v;
  }
}

// ---------------------------------------------------------------------------
// feat fp32 NCHW -> padded f16, layout [cb16][n][hp][wp][16ci], halo pre-zeroed
// ---------------------------------------------------------------------------
__global__ __launch_bounds__(256)
void convert_k(const float* __restrict__ x, _Float16* __restrict__ act,
               int H, int W)
{
  const int h = blockIdx.x, n = blockIdx.y;
  const int Hp = H + 2, Wp = W + 2, HpWp = Hp * Wp;
  const unsigned CBS = 2u * (unsigned)HpWp * 16u;  // halfs per cb chunk (N=2)
  __shared__ float s[64][154];
  for (int c0 = 0; c0 < 256; c0 += 64) {
    for (int idx = threadIdx.x; idx < 64 * W; idx += 256) {
      int c = idx / W, w = idx - c * W;
      s[c][w] = x[((size_t)(n * 256 + c0 + c) * H + h) * W + w];
    }
    __syncthreads();
    for (int idx = threadIdx.x; idx < 4 * W; idx += 256) {
      int ch = idx / W, w = idx - ch * W;
      int cchunk = (c0 >> 4) + ch;
      unsigned base = (unsigned)cchunk * CBS +
                      ((unsigned)((n * Hp + h + 1) * Wp + (w + 1))) * 16u;
      f16x8 v0, v1;
#pragma unroll
      for (int j = 0; j < 8; ++j) {
        v0[j] = (_Float16)s[ch * 16 + j][w];
        v1[j] = (_Float16)s[ch * 16 + 8 + j][w];
      }
      *(f16x8*)(act + base) = v0;
      *(f16x8*)(act + base + 8) = v1;
    }
    __syncthreads();
  }
}

// ---------------------------------------------------------------------------
// Implicit-GEMM conv3x3 via mfma_f32_32x32x16_f16, fused dual-chain.
// MODE 0 = towers: blockIdx.y = chain*4 + cg; relu -> f16 act out.
// MODE 1 = heads (per image): blockIdx.y<12 -> cls head (sigmoid->P,
//          mloc*720+co); ==12 -> bbox head (raw->R, mglobal*36+co).
// One wave per block; wave tile 64(M) x 64(CO): 4 accumulators.
// ---------------------------------------------------------------------------
template<int MODE>
__global__ __launch_bounds__(64)
void conv_f16_k(const _Float16* __restrict__ inA, const _Float16* __restrict__ inB,
                const _Float16* __restrict__ wpkBase,
                const float* __restrict__ biasA, const float* __restrict__ biasB,
                _Float16* __restrict__ outA, _Float16* __restrict__ outB,
                float* __restrict__ P, float* __restrict__ R,
                int H, int W, int mBase, int Mloc,
                unsigned wOffA, unsigned wOffB)
{
  const int Wp = W + 2;
  const int HW = H * W;
  const int HpWp = (H + 2) * Wp;
  const unsigned CBS = 2u * (unsigned)HpWp * 16u;

  const int y = blockIdx.y;
  const _Float16* in;
  const _Float16* w;
  const float* bias;
  _Float16* out = nullptr;
  int Cout, nCoF, coF0, coBase;
  if (MODE == 0) {
    const int chain = y >> 2, cg = y & 3;
    in = chain ? inB : inA;
    w = wpkBase + (chain ? wOffB : wOffA);
    bias = chain ? biasB : biasA;
    out = chain ? outB : outA;
    Cout = 256; nCoF = 8; coF0 = cg * 2; coBase = cg * 64;
  } else {
    if (y < 12) {
      in = inA; w = wpkBase + wOffA; bias = biasA;
      Cout = 720; nCoF = 24; coF0 = y * 2; coBase = y * 64;
    } else {
      in = inB; w = wpkBase + wOffB; bias = biasB;
      Cout = 36; nCoF = 2; coF0 = 0; coBase = 0;
    }
  }

  const int l = threadIdx.x;
  const int lw = l & 31;
  const int lh = l >> 5;

  unsigned V[2];
#pragma unroll
  for (int i = 0; i < 2; ++i) {
    int mloc = blockIdx.x * 64 + i * 32 + lw;
    if (mloc >= Mloc) mloc = Mloc - 1;
    int mg = mBase + mloc;
    int n = mg / HW; int rem = mg - n * HW;
    int h = rem / W; int ww = rem - h * W;
    V[i] = ((unsigned)(n * HpWp + h * Wp + ww)) * 16u + (unsigned)lh * 8u;
  }

  const unsigned lOff = (unsigned)l * 8u;
  f32x16 acc00 = {}, acc01 = {}, acc10 = {}, acc11 = {};

  for (int cb = 0; cb < 16; ++cb) {
    const _Float16* aB = in + (unsigned)cb * CBS;
    const _Float16* wB = w + ((unsigned)cb * (unsigned)nCoF + (unsigned)coF0) * 512u;
#pragma unroll
    for (int tap = 0; tap < 9; ++tap) {
      const unsigned to = ((unsigned)((tap / 3) * Wp + (tap % 3))) * 16u;
      const _Float16* wT = wB + (unsigned)tap * 16u * (unsigned)nCoF * 512u;
      f16x8 a0 = *(const f16x8*)(aB + to + V[0]);
      f16x8 a1 = *(const f16x8*)(aB + to + V[1]);
      f16x8 b0 = *(const f16x8*)(wT + lOff);
      f16x8 b1 = *(const f16x8*)(wT + 512u + lOff);
      acc00 = __builtin_amdgcn_mfma_f32_32x32x16_f16(a0, b0, acc00, 0, 0, 0);
      acc01 = __builtin_amdgcn_mfma_f32_32x32x16_f16(a0, b1, acc01, 0, 0, 0);
      acc10 = __builtin_amdgcn_mfma_f32_32x32x16_f16(a1, b0, acc10, 0, 0, 0);
      acc11 = __builtin_amdgcn_mfma_f32_32x32x16_f16(a1, b1, acc11, 0, 0, 0);
    }
  }

  auto emit = [&](const f32x16& A, int i, int f) {
    const int co = coBase + f * 32 + lw;
    const float bv = (co < Cout) ? bias[co] : 0.f;
#pragma unroll
    for (int r = 0; r < 16; ++r) {
      int mloc = blockIdx.x * 64 + i * 32 + ((r & 3) + 8 * (r >> 2) + 4 * lh);
      if (mloc >= Mloc) continue;
      float v = A[r] + bv;
      if (MODE == 0) {
        if (co < Cout) {
          int mg = mloc;  // mBase==0 for towers
          int n = mg / HW; int rem = mg - n * HW;
          int h = rem / W; int ww = rem - h * W;
          unsigned addr = ((unsigned)(co >> 4)) * CBS +
                          ((unsigned)(n * HpWp + (h + 1) * Wp + (ww + 1))) * 16u +
                          (unsigned)(co & 15);
          out[addr] = (_Float16)fmaxf(v, 0.f);
        }
      } else {
        if (y < 12) {
          if (co < 720) P[(size_t)mloc * 720 + co] = 1.f / (1.f + expf(-v));
        } else {
          if (co < 36) R[(size_t)(mBase + mloc) * 36 + co] = v;
        }
      }
    }
  };
  emit(acc00, 0, 0); emit(acc01, 0, 1); emit(acc10, 1, 0); emit(acc11, 1, 1);
}

// ---------------- top-k: 2-level radix select (per image) ----------------
__global__ __launch_bounds__(256)
void hist_coarse_k(const float* __restrict__ P, int M, unsigned* __restrict__ histC)
{
  __shared__ unsigned lh[4096];
  for (int i = threadIdx.x; i < 4096; i += 256) lh[i] = 0;
  __syncthreads();
  for (int i = blockIdx.x * 256 + threadIdx.x; i < M; i += gridDim.x * 256) {
    unsigned b = __float_as_uint(P[i]) >> 18;
    atomicAdd(&lh[b & 4095u], 1u);
  }
  __syncthreads();
  for (int i = threadIdx.x; i < 4096; i += 256) {
    unsigned c = lh[i];
    if (c) atomicAdd(&histC[i], c);
  }
}

__global__ __launch_bounds__(256)
void hist_fine_k(const float* __restrict__ P, int M, const unsigned* __restrict__ sel,
                 unsigned* __restrict__ histF)
{
  const unsigned cb = sel[0];
  for (int i = blockIdx.x * 256 + threadIdx.x; i < M; i += gridDim.x * 256) {
    unsigned b = __float_as_uint(P[i]);
    if ((b >> 18) == cb) atomicAdd(&histF[b & 0x3FFFFu], 1u);
  }
}

__global__ __launch_bounds__(1024)
void radix_scan_k(const unsigned* __restrict__ hist, int nbins,
                  unsigned* __restrict__ s, int k, int phase)
{
  const int per = nbins / 1024;
  const int tid = threadIdx.x;
  unsigned local = 0;
  const unsigned* hb = hist + tid * per;
  for (int i = 0; i < per; ++i) local += hb[i];
  __shared__ unsigned part[1024];
  part[tid] = local;
  __syncthreads();
  // inclusive suffix scan (Hillis-Steele)
  for (int d = 1; d < 1024; d <<= 1) {
    unsigned v = (tid + d < 1024) ? part[tid + d] : 0u;
    __syncthreads();
    part[tid] += v;
    __syncthreads();
  }
  unsigned above = part[tid] - local;
  unsigned kk = (phase == 0) ? (unsigned)k : ((unsigned)k - s[1]);
  if (above < kk && above + local >= kk) {
    unsigned cum = above;
    for (int i = per - 1; i >= 0; --i) {
      unsigned c = hb[i];
      if (cum + c >= kk) {
        if (phase == 0) { s[0] = (unsigned)(tid * per + i); s[1] = cum; }
        else { s[2] = (s[0] << 18) | (unsigned)(tid * per + i); s[4] = kk - cum; }
        break;
      }
      cum += c;
    }
  }
}

__global__ __launch_bounds__(256)
void compact_k(const float* __restrict__ P, int M, unsigned* __restrict__ s,
               float* __restrict__ cv, unsigned* __restrict__ ci, unsigned* __restrict__ eq)
{
  const unsigned thr = s[2];
  for (int i = blockIdx.x * 256 + threadIdx.x; i < M; i += gridDim.x * 256) {
    unsigned b = __float_as_uint(P[i]);
    if (b > thr) {
      unsigned g = atomicAdd(&s[5], 1u);
      if (g < 1024u) { cv[g] = P[i]; ci[g] = (unsigned)i; }
    } else if (b == thr) {
      unsigned e = atomicAdd(&s[6], 1u);
      if (e < 8192u) eq[e] = (unsigned)i;
    }
  }
}

__global__ __launch_bounds__(1024)
void finalize_k(const float* __restrict__ cv, const unsigned* __restrict__ ci,
                const unsigned* __restrict__ eq, const unsigned* __restrict__ s,
                const float* __restrict__ R, const float* __restrict__ anc,
                int k, int outBase, int HWA, int n,
                float* __restrict__ candB, float* __restrict__ candS, float* __restrict__ candC)
{
  const int tid = threadIdx.x;
  __shared__ float svals[1024];
  __shared__ unsigned sidx[1024];
  __shared__ unsigned long long key[1024];
  const unsigned cntG = s[5] < 1024u ? s[5] : 1024u;
  const unsigned nEq = s[4];
  if (tid < (int)cntG) { svals[tid] = cv[tid]; sidx[tid] = ci[tid]; }
  __syncthreads();
  if (tid == 0) {
    unsigned cnt = s[6] < 8192u ? s[6] : 8192u;
    unsigned last = 0; int first = 1;
    float tv = __uint_as_float(s[2]);
    for (unsigned e2 = 0; e2 < nEq && cntG + e2 < 1024u; ++e2) {
      unsigned best = 0xFFFFFFFFu;
      for (unsigned q = 0; q < cnt; ++q) {
        unsigned v = eq[q];
        if ((first || v > last) && v < best) best = v;
      }
      svals[cntG + e2] = tv; sidx[cntG + e2] = best;
      last = best; first = 0;
    }
  }
  __syncthreads();
  const int kk = (int)cntG + (int)nEq;
  key[tid] = (tid < kk)
      ? (((unsigned long long)__float_as_uint(svals[tid]) << 32) |
         (unsigned long long)(0xFFFFFFFFu - sidx[tid]))
      : 0ULL;
  __syncthreads();
  for (int sz = 2; sz <= 1024; sz <<= 1) {
    for (int st = sz >> 1; st > 0; st >>= 1) {
      int ixj = tid ^ st;
      if (ixj > tid) {
        unsigned long long a = key[tid], b = key[ixj];
        bool up = ((tid & sz) == 0);
        if (up ? (a < b) : (a > b)) { key[tid] = b; key[ixj] = a; }
      }
      __syncthreads();
    }
  }
  if (tid < kk && tid < k) {
    unsigned long long kv = key[tid];
    float val = __uint_as_float((unsigned)(kv >> 32));
    unsigned idx = 0xFFFFFFFFu - (unsigned)(kv & 0xFFFFFFFFu);
    unsigned a = idx / 80u;
    unsigned cls = idx - a * 80u;
    const float* rg = R + ((size_t)n * HWA + a) * 4;
    float a0 = anc[(size_t)a * 4 + 0], a1 = anc[(size_t)a * 4 + 1];
    float a2 = anc[(size_t)a * 4 + 2], a3 = anc[(size_t)a * 4 + 3];
    float wa = a2 - a0, ha = a3 - a1;
    float xa = a0 + 0.5f * wa, ya = a1 + 0.5f * ha;
    float dx = rg[0], dy = rg[1];
    float dw = fminf(rg[2], SCALE_CLAMP_F), dh = fminf(rg[3], SCALE_CLAMP_F);
    float cx = dx * wa + xa, cy = dy * ha + ya;
    float wb = expf(dw) * wa, hb = expf(dh) * ha;
    float x0 = cx - 0.5f * wb, y0 = cy - 0.5f * hb;
    float x1 = cx + 0.5f * wb, y1 = cy + 0.5f * hb;
    x0 = fminf(fmaxf(x0, 0.f), IMG_W_F);
    y0 = fminf(fmaxf(y0, 0.f), IMG_H_F);
    x1 = fminf(fmaxf(x1, 0.f), IMG_W_F);
    y1 = fminf(fmaxf(y1, 0.f), IMG_H_F);
    int o = outBase + tid;
    candB[(size_t)o * 4 + 0] = x0; candB[(size_t)o * 4 + 1] = y0;
    candB[(size_t)o * 4 + 2] = x1; candB[(size_t)o * 4 + 3] = y1;
    candS[o] = (val > SCORE_THR) ? val : 0.f;
    candC[o] = (float)cls;
  }
}

// ---------------- class-aware NMS, one block per image ----------------
__global__ __launch_bounds__(1024)
void nms_k(const float* __restrict__ cB, const float* __restrict__ cS,
           const float* __restrict__ cC, float* __restrict__ out)
{
  const int n = blockIdx.x;
  const int tid = threadIdx.x;
  __shared__ float S[NCAND];
  __shared__ float rv[1024];
  __shared__ int ri[1024];
  __shared__ float bj[4];
  for (int i = tid; i < NCAND; i += 1024) S[i] = cS[n * NCAND + i];
  __syncthreads();
  for (int it = 0; it < MAXDET; ++it) {
    float bv = -1.f; int bix = 0;
    for (int i = tid; i < NCAND; i += 1024) {
      float v = S[i];
      if (v > bv) { bv = v; bix = i; }
    }
    rv[tid] = bv; ri[tid] = bix;
    __syncthreads();
    for (int st = 512; st > 0; st >>= 1) {
      if (tid < st) {
        float v2 = rv[tid + st]; int i2 = ri[tid + st];
        if (v2 > rv[tid] || (v2 == rv[tid] && i2 < ri[tid])) { rv[tid] = v2; ri[tid] = i2; }
      }
      __syncthreads();
    }
    const int j = ri[0];
    const float mv = rv[0];
    if (mv <= 0.f) {
      float b0 = cB[(size_t)(n * NCAND) * 4 + 0], b1 = cB[(size_t)(n * NCAND) * 4 + 1];
      float b2 = cB[(size_t)(n * NCAND) * 4 + 2], b3 = cB[(size_t)(n * NCAND) * 4 + 3];
      float c0 = cC[n * NCAND];
      for (int t2 = it + tid; t2 < MAXDET; t2 += 1024) {
        out[((size_t)n * MAXDET + t2) * 4 + 0] = b0;
        out[((size_t)n * MAXDET + t2) * 4 + 1] = b1;
        out[((size_t)n * MAXDET + t2) * 4 + 2] = b2;
        out[((size_t)n * MAXDET + t2) * 4 + 3] = b3;
        out[800 + n * MAXDET + t2] = 0.f;
        out[1000 + n * MAXDET + t2] = c0;
      }
      return;
    }
    if (tid == 0) {
      out[((size_t)n * MAXDET + it) * 4 + 0] = cB[(size_t)(n * NCAND + j) * 4 + 0];
      out[((size_t)n * MAXDET + it) * 4 + 1] = cB[(size_t)(n * NCAND + j) * 4 + 1];
      out[((size_t)n * MAXDET + it) * 4 + 2] = cB[(size_t)(n * NCAND + j) * 4 + 2];
      out[((size_t)n * MAXDET + it) * 4 + 3] = cB[(size_t)(n * NCAND + j) * 4 + 3];
      out[800 + n * MAXDET + it] = mv;
      out[1000 + n * MAXDET + it] = cC[n * NCAND + j];
      float off = cC[n * NCAND + j] * 4096.f;
      bj[0] = cB[(size_t)(n * NCAND + j) * 4 + 0] + off;
      bj[1] = cB[(size_t)(n * NCAND + j) * 4 + 1] + off;
      bj[2] = cB[(size_t)(n * NCAND + j) * 4 + 2] + off;
      bj[3] = cB[(size_t)(n * NCAND + j) * 4 + 3] + off;
    }
    __syncthreads();
    const float jx0 = bj[0], jy0 = bj[1], jx1 = bj[2], jy1 = bj[3];
    const float aj = (jx1 - jx0) * (jy1 - jy0);
    for (int i = tid; i < NCAND; i += 1024) {
      if (S[i] == 0.f) continue;
      float off = cC[n * NCAND + i] * 4096.f;
      float x0 = cB[(size_t)(n * NCAND + i) * 4 + 0] + off;
      float y0 = cB[(size_t)(n * NCAND + i) * 4 + 1] + off;
      float x1 = cB[(size_t)(n * NCAND + i) * 4 + 2] + off;
      float y1 = cB[(size_t)(n * NCAND + i) * 4 + 3] + off;
      float lx = fmaxf(jx0, x0), ly = fmaxf(jy0, y0);
      float rx = fminf(jx1, x1), ry = fminf(jy1, y1);
      float iw = fmaxf(rx - lx, 0.f), ih = fmaxf(ry - ly, 0.f);
      float inter = iw * ih;
      float ai = (x1 - x0) * (y1 - y0);
      float iou = inter / (aj + ai - inter + 1e-9f);
      if (iou > NMS_THR) S[i] = 0.f;
    }
    if (tid == 0) S[j] = 0.f;
    __syncthreads();
  }
}

// ---------------- host ----------------
extern "C" void kernel_launch(void* const* d_in, const int* in_sizes, int n_in,
                              void* d_out, int out_size, void* d_ws, size_t ws_size,
                              hipStream_t stream)
{
  static const int LH[5] = {100, 50, 25, 13, 7};
  static const int LW[5] = {152, 76, 38, 19, 10};
  static const int NTK[5] = {1000, 1000, 1000, 1000, 630};
  static const int OFFS[5] = {0, 1000, 2000, 3000, 4000};

  const float* feat[5]; const float* anc[5];
  for (int l = 0; l < 5; ++l) {
    feat[l] = (const float*)d_in[l];
    anc[l] = (const float*)d_in[13 + l];
  }
  const float* csw = (const float*)d_in[5];
  const float* csb = (const float*)d_in[6];
  const float* bsw = (const float*)d_in[7];
  const float* bsb = (const float*)d_in[8];
  const float* scw = (const float*)d_in[9];
  const float* scb = (const float*)d_in[10];
  const float* bpw = (const float*)d_in[11];
  const float* bpb = (const float*)d_in[12];

  float* ws = (float*)d_ws;
  size_t o = 0;
  _Float16* actBase = (_Float16*)(ws + o); o += 16084992;  // 4 bufs x 8,042,496 halfs
  _Float16* wpk = (_Float16*)(ws + o); o += 3317760;       // 6,635,520 halfs
  float* P = ws + o; o += 10944000;                        // per-image probs (L0)
  float* R = ws + o; o += 1094400;                         // both-image deltas (L0)
  float* candB = ws + o; o += (size_t)NIMG * NCAND * 4;
  float* candS = ws + o; o += NIMG * NCAND;
  float* candC = ws + o; o += NIMG * NCAND;
  float* candV = ws + o; o += NIMG * 1024;
  unsigned* candI = (unsigned*)(ws + o); o += NIMG * 1024;
  unsigned* eqI = (unsigned*)(ws + o); o += NIMG * 8192;
  unsigned* histC = (unsigned*)(ws + o); o += NIMG * 4096;
  unsigned* histF = (unsigned*)(ws + o); o += NIMG * 262144;
  unsigned* sel = (unsigned*)(ws + o); o += NIMG * 8;
  if (ws_size < o * sizeof(float)) return;  // ~128 MB required

  float* out = (float*)d_out;

  // --- weight prepack (10 convs, f16 single plane) ---
  for (int i = 0; i < 4; ++i) {
    int tot = 9 * 16 * 8 * 64;
    prepack_k<<<dim3((tot + 255) / 256), dim3(256), 0, stream>>>(
        csw + (size_t)i * 589824, wpk + WOFF_CLS_T(i), 256, 8);
    prepack_k<<<dim3((tot + 255) / 256), dim3(256), 0, stream>>>(
        bsw + (size_t)i * 589824, wpk + WOFF_BBX_T(i), 256, 8);
  }
  {
    int tot = 9 * 16 * 24 * 64;
    prepack_k<<<dim3((tot + 255) / 256), dim3(256), 0, stream>>>(scw, wpk + WOFF_CLS_H, 720, 24);
    tot = 9 * 16 * 2 * 64;
    prepack_k<<<dim3((tot + 255) / 256), dim3(256), 0, stream>>>(bpw, wpk + WOFF_BBX_H, 36, 2);
  }

  for (int l = 0; l < 5; ++l) {
    const int H = LH[l], W = LW[l];
    const int HW = H * W, Hp = H + 2, Wp = W + 2;
    const int HpWp = Hp * Wp;
    const int HWA = HW * 9;
    const int M = HW * 720;
    const int k = NTK[l];

    // per-level act buffers (contiguous): X, A, B, C
    const size_t bufHalfs = (size_t)HpWp * 512;  // 16cb*2img*16ci
    _Float16* X = actBase;
    _Float16* A = X + bufHalfs;
    _Float16* B = A + bufHalfs;
    _Float16* C = B + bufHalfs;
    hipMemsetAsync(X, 0, 4 * bufHalfs * sizeof(_Float16), stream);

    const int Mtot = 2 * HW;
    const int gmT = (Mtot + 63) / 64;
    const int gmH = (HW + 63) / 64;

    convert_k<<<dim3(H, NIMG), dim3(256), 0, stream>>>(feat[l], X, H, W);
    // fused towers: chain0 = cls, chain1 = bbox
    conv_f16_k<0><<<dim3(gmT, 8), dim3(64), 0, stream>>>(
        X, X, wpk, csb + 0, bsb + 0, A, B, nullptr, nullptr,
        H, W, 0, Mtot, WOFF_CLS_T(0), WOFF_BBX_T(0));
    conv_f16_k<0><<<dim3(gmT, 8), dim3(64), 0, stream>>>(
        A, B, wpk, csb + 256, bsb + 256, C, X, nullptr, nullptr,
        H, W, 0, Mtot, WOFF_CLS_T(1), WOFF_BBX_T(1));
    conv_f16_k<0><<<dim3(gmT, 8), dim3(64), 0, stream>>>(
        C, X, wpk, csb + 512, bsb + 512, A, B, nullptr, nullptr,
        H, W, 0, Mtot, WOFF_CLS_T(2), WOFF_BBX_T(2));
    conv_f16_k<0><<<dim3(gmT, 8), dim3(64), 0, stream>>>(
        A, B, wpk, csb + 768, bsb + 768, C, X, nullptr, nullptr,
        H, W, 0, Mtot, WOFF_CLS_T(3), WOFF_BBX_T(3));

    hipMemsetAsync(histC, 0, NIMG * 4096 * sizeof(unsigned), stream);
    hipMemsetAsync(histF, 0, (size_t)NIMG * 262144 * sizeof(unsigned), stream);
    hipMemsetAsync(sel, 0, NIMG * 8 * sizeof(unsigned), stream);

    for (int n = 0; n < NIMG; ++n) {
      // fused heads: y<12 cls (C -> P), y==12 bbox (X -> R)
      conv_f16_k<1><<<dim3(gmH, 13), dim3(64), 0, stream>>>(
          C, X, wpk, scb, bpb, nullptr, nullptr, P, R,
          H, W, n * HW, HW, WOFF_CLS_H, WOFF_BBX_H);
      unsigned* sel_n = sel + n * 8;
      hist_coarse_k<<<dim3(256), dim3(256), 0, stream>>>(P, M, histC + n * 4096);
      radix_scan_k<<<dim3(1), dim3(1024), 0, stream>>>(histC + n * 4096, 4096, sel_n, k, 0);
      hist_fine_k<<<dim3(256), dim3(256), 0, stream>>>(P, M, sel_n, histF + (size_t)n * 262144);
      radix_scan_k<<<dim3(1), dim3(1024), 0, stream>>>(histF + (size_t)n * 262144, 262144, sel_n, k, 1);
      compact_k<<<dim3(256), dim3(256), 0, stream>>>(P, M, sel_n,
          candV + n * 1024, candI + n * 1024, eqI + (size_t)n * 8192);
      finalize_k<<<dim3(1), dim3(1024), 0, stream>>>(
          candV + n * 1024, candI + n * 1024, eqI + (size_t)n * 8192, sel_n,
          R, anc[l], k, n * NCAND + OFFS[l], HWA, n, candB, candS, candC);
    }
  }
  nms_k<<<dim3(NIMG), dim3(1024), 0, stream>>>(candB, candS, candC, out);
}

// Round 5
// 2154.579 us; speedup vs baseline: 9.8071x; 1.8555x over previous
//
#include <hip/hip_runtime.h>
#include <math.h>

#define NIMG 2
#define NCAND 4630
#define MAXDET 100
#define IMG_W_F 1216.0f
#define IMG_H_F 800.0f
#define SCORE_THR 0.05f
#define NMS_THR 0.5f
#define SCALE_CLAMP_F 4.135166556742356f  // log(1000/16)

typedef __attribute__((ext_vector_type(8))) _Float16 f16x8;
typedef __attribute__((ext_vector_type(16))) float f32x16;

// weight-pack offsets in halfs: [clsT0..3][bbxT0..3][clsHead][bbxHead]
#define WOFF_CLS_T(i) ((unsigned)(i) * 589824u)
#define WOFF_BBX_T(i) (2359296u + (unsigned)(i) * 589824u)
#define WOFF_CLS_H 4718592u
#define WOFF_BBX_H 6488064u

#define BUF_HALFS 10888704u  // per act buffer (all levels, both images)

struct ConvTab {
  int cum[6];
  int H[5], W[5];
  unsigned actOff[5];
};
struct CvtTab {
  const float* f[5];
  int cumR[6];
  int H[5], W[5];
  unsigned actOff[5];
};
struct HeadTab {
  int cum[6];
  unsigned actOff[5];
  int H[5], W[5];
  int pOffL[5];
  int rOffL[5];
  int imgBase;
  int pImgStride;
};
struct TKTab {
  int pOff[8]; int M[8]; int kk[8]; int rBase[8]; int outBase[8];
  const float* anc[8];
};

// ---------------------------------------------------------------------------
// Weight prepack: OIHW fp32 -> [tap][cb16][coF][lane64][8] f16 frags
// ---------------------------------------------------------------------------
__global__ __launch_bounds__(256)
void prepack_k(const float* __restrict__ src, _Float16* __restrict__ dst,
               int Cout, int nCoF)
{
  const int total = 9 * 16 * nCoF * 64;
  int t = blockIdx.x * 256 + threadIdx.x;
  if (t >= total) return;
  const int l = t & 63;
  const int rest = t >> 6;
  const int coF = rest % nCoF;
  const int tc = rest / nCoF;
  const int tap = tc >> 4;
  const int cb = tc & 15;
  const int co = coF * 32 + (l & 31);
  const int ciB = cb * 16 + (l >> 5) * 8;
#pragma unroll
  for (int j = 0; j < 8; ++j) {
    float v = 0.f;
    if (co < Cout) v = src[(size_t)(co * 256 + ciB + j) * 9 + tap];
    dst[(size_t)t * 8 + j] = (_Float16)v;
  }
}

// ---------------------------------------------------------------------------
// feat fp32 NCHW -> padded f16 [cb16][n][hp][wp][16ci]; all levels batched
// ---------------------------------------------------------------------------
__global__ __launch_bounds__(256)
void convert_k(_Float16* __restrict__ act, CvtTab tb)
{
  int bz = blockIdx.x;
  int l = 0;
#pragma unroll
  for (int i = 1; i < 5; ++i) if (bz >= tb.cumR[i]) l = i;
  const int h = bz - tb.cumR[l];
  const int n = blockIdx.y;
  const int H = tb.H[l], W = tb.W[l];
  const int Hp = H + 2, Wp = W + 2, HpWp = Hp * Wp;
  const unsigned CBS = 2u * (unsigned)HpWp * 16u;
  const float* x = tb.f[l];
  _Float16* a = act + tb.actOff[l];
  __shared__ float s[64][154];
  for (int c0 = 0; c0 < 256; c0 += 64) {
    for (int idx = threadIdx.x; idx < 64 * W; idx += 256) {
      int c = idx / W, w = idx - c * W;
      s[c][w] = x[((size_t)(n * 256 + c0 + c) * H + h) * W + w];
    }
    __syncthreads();
    for (int idx = threadIdx.x; idx < 4 * W; idx += 256) {
      int ch = idx / W, w = idx - ch * W;
      int cchunk = (c0 >> 4) + ch;
      unsigned base = (unsigned)cchunk * CBS +
                      ((unsigned)((n * Hp + h + 1) * Wp + (w + 1))) * 16u;
      f16x8 v0, v1;
#pragma unroll
      for (int j = 0; j < 8; ++j) {
        v0[j] = (_Float16)s[ch * 16 + j][w];
        v1[j] = (_Float16)s[ch * 16 + 8 + j][w];
      }
      *(f16x8*)(a + base) = v0;
      *(f16x8*)(a + base + 8) = v1;
    }
    __syncthreads();
  }
}

// ---------------------------------------------------------------------------
// shared conv inner loop: 16 cb-chunks x 9 taps x 4 mfma_32x32x16_f16
// ---------------------------------------------------------------------------
__device__ __forceinline__ void conv_core(
    const _Float16* __restrict__ in, const _Float16* __restrict__ w,
    int nCoF, int coF0, int Wp, unsigned CBS, const unsigned V0, const unsigned V1,
    unsigned lOff, f32x16& a00, f32x16& a01, f32x16& a10, f32x16& a11)
{
  for (int cb = 0; cb < 16; ++cb) {
    const _Float16* aB = in + (unsigned)cb * CBS;
    const _Float16* wB = w + ((unsigned)cb * (unsigned)nCoF + (unsigned)coF0) * 512u;
#pragma unroll
    for (int tap = 0; tap < 9; ++tap) {
      const unsigned to = ((unsigned)((tap / 3) * Wp + (tap % 3))) * 16u;
      const _Float16* wT = wB + (unsigned)tap * 16u * (unsigned)nCoF * 512u;
      f16x8 a0 = *(const f16x8*)(aB + to + V0);
      f16x8 a1 = *(const f16x8*)(aB + to + V1);
      f16x8 b0 = *(const f16x8*)(wT + lOff);
      f16x8 b1 = *(const f16x8*)(wT + 512u + lOff);
      a00 = __builtin_amdgcn_mfma_f32_32x32x16_f16(a0, b0, a00, 0, 0, 0);
      a01 = __builtin_amdgcn_mfma_f32_32x32x16_f16(a0, b1, a01, 0, 0, 0);
      a10 = __builtin_amdgcn_mfma_f32_32x32x16_f16(a1, b0, a10, 0, 0, 0);
      a11 = __builtin_amdgcn_mfma_f32_32x32x16_f16(a1, b1, a11, 0, 0, 0);
    }
  }
}

// ---------------------------------------------------------------------------
// Towers, all levels + both chains + both images in one dispatch.
// grid: (cumT[5], 8); y = chain*4 + cg
// ---------------------------------------------------------------------------
__global__ __launch_bounds__(64)
void tower_k(const _Float16* __restrict__ inA, const _Float16* __restrict__ inB,
             const _Float16* __restrict__ wpk,
             const float* __restrict__ biasA, const float* __restrict__ biasB,
             _Float16* __restrict__ outA, _Float16* __restrict__ outB,
             unsigned wOffA, unsigned wOffB, ConvTab tb)
{
  int bz = blockIdx.x;
  int l = 0;
#pragma unroll
  for (int i = 1; i < 5; ++i) if (bz >= tb.cum[i]) l = i;
  const int bx = bz - tb.cum[l];
  const int H = tb.H[l], W = tb.W[l];
  const int Wp = W + 2, HW = H * W, HpWp = (H + 2) * Wp;
  const unsigned CBS = 2u * (unsigned)HpWp * 16u;
  const int chain = blockIdx.y >> 2, cg = blockIdx.y & 3;
  const _Float16* in = (chain ? inB : inA) + tb.actOff[l];
  _Float16* out = (chain ? outB : outA) + tb.actOff[l];
  const _Float16* w = wpk + (chain ? wOffB : wOffA);
  const float* bias = chain ? biasB : biasA;
  const int Mloc = 2 * HW;

  const int lane = threadIdx.x;
  const int lw = lane & 31;
  const int lh = lane >> 5;
  unsigned V[2];
#pragma unroll
  for (int i = 0; i < 2; ++i) {
    int mloc = bx * 64 + i * 32 + lw;
    if (mloc >= Mloc) mloc = Mloc - 1;
    int n = mloc / HW; int rem = mloc - n * HW;
    int h = rem / W; int ww = rem - h * W;
    V[i] = ((unsigned)(n * HpWp + h * Wp + ww)) * 16u + (unsigned)lh * 8u;
  }
  f32x16 a00 = {}, a01 = {}, a10 = {}, a11 = {};
  conv_core(in, w, 8, cg * 2, Wp, CBS, V[0], V[1], (unsigned)lane * 8u,
            a00, a01, a10, a11);

  const int coBase = cg * 64;
  const f32x16* accs[4] = {&a00, &a01, &a10, &a11};
#pragma unroll
  for (int q = 0; q < 4; ++q) {
    const f32x16& A = *accs[q];
    const int i = q >> 1, f = q & 1;
    const int co = coBase + f * 32 + lw;
    const float bv = bias[co];
#pragma unroll
    for (int r = 0; r < 16; ++r) {
      int mloc = bx * 64 + i * 32 + ((r & 3) + 8 * (r >> 2) + 4 * lh);
      if (mloc >= Mloc) continue;
      int n = mloc / HW; int rem = mloc - n * HW;
      int h = rem / W; int ww = rem - h * W;
      unsigned addr = ((unsigned)(co >> 4)) * CBS +
                      ((unsigned)(n * HpWp + (h + 1) * Wp + (ww + 1))) * 16u +
                      (unsigned)(co & 15);
      out[addr] = (_Float16)fmaxf(A[r] + bv, 0.f);
    }
  }
}

// ---------------------------------------------------------------------------
// Heads over a level subset; z = image offset. y<12: cls->P(sigmoid); y==12: bbox->R(f16)
// ---------------------------------------------------------------------------
__global__ __launch_bounds__(64)
void head_k(const _Float16* __restrict__ inC, const _Float16* __restrict__ inX,
            const _Float16* __restrict__ wpk,
            const float* __restrict__ scb, const float* __restrict__ bpb,
            float* __restrict__ P, _Float16* __restrict__ Rh, HeadTab tb)
{
  int bz = blockIdx.x;
  int li = 0;
#pragma unroll
  for (int i = 1; i < 5; ++i) if (bz >= tb.cum[i]) li = i;
  const int bx = bz - tb.cum[li];
  const int H = tb.H[li], W = tb.W[li];
  const int Wp = W + 2, HW = H * W, HpWp = (H + 2) * Wp;
  const unsigned CBS = 2u * (unsigned)HpWp * 16u;
  const int img = tb.imgBase + blockIdx.z;
  const int y = blockIdx.y;

  const _Float16* in;
  const _Float16* w;
  const float* bias;
  int nCoF, coF0, coBase, Cout;
  if (y < 12) {
    in = inC + tb.actOff[li]; w = wpk + WOFF_CLS_H; bias = scb;
    nCoF = 24; coF0 = y * 2; coBase = y * 64; Cout = 720;
  } else {
    in = inX + tb.actOff[li]; w = wpk + WOFF_BBX_H; bias = bpb;
    nCoF = 2; coF0 = 0; coBase = 0; Cout = 36;
  }
  const int Mloc = HW;
  const int lane = threadIdx.x;
  const int lw = lane & 31;
  const int lh = lane >> 5;
  unsigned V[2];
#pragma unroll
  for (int i = 0; i < 2; ++i) {
    int mloc = bx * 64 + i * 32 + lw;
    if (mloc >= Mloc) mloc = Mloc - 1;
    int h = mloc / W; int ww = mloc - h * W;
    V[i] = ((unsigned)(img * HpWp + h * Wp + ww)) * 16u + (unsigned)lh * 8u;
  }
  f32x16 a00 = {}, a01 = {}, a10 = {}, a11 = {};
  conv_core(in, w, nCoF, coF0, Wp, CBS, V[0], V[1], (unsigned)lane * 8u,
            a00, a01, a10, a11);

  const size_t pBase = (size_t)tb.pOffL[li] + (size_t)blockIdx.z * tb.pImgStride;
  const size_t rBase = (size_t)tb.rOffL[li] + (size_t)img * HW * 36;
  const f32x16* accs[4] = {&a00, &a01, &a10, &a11};
#pragma unroll
  for (int q = 0; q < 4; ++q) {
    const f32x16& A = *accs[q];
    const int i = q >> 1, f = q & 1;
    const int co = coBase + f * 32 + lw;
    const float bv = (co < Cout) ? bias[co] : 0.f;
#pragma unroll
    for (int r = 0; r < 16; ++r) {
      int mloc = bx * 64 + i * 32 + ((r & 3) + 8 * (r >> 2) + 4 * lh);
      if (mloc >= Mloc) continue;
      float v = A[r] + bv;
      if (y < 12) {
        if (co < 720) P[pBase + (size_t)mloc * 720 + co] = 1.f / (1.f + expf(-v));
      } else {
        if (co < 36) Rh[rBase + (size_t)mloc * 36 + co] = (_Float16)v;
      }
    }
  }
}

// ---------------- top-k: 2-level radix select, slot-batched ----------------
__global__ __launch_bounds__(256)
void hist_coarse_k(const float* __restrict__ P, unsigned* __restrict__ histC, TKTab t)
{
  const int slot = blockIdx.y;
  __shared__ unsigned lh[8192];
  for (int i = threadIdx.x; i < 8192; i += 256) lh[i] = 0;
  __syncthreads();
  const float* p = P + t.pOff[slot];
  const int M = t.M[slot];
  for (int i = blockIdx.x * 256 + threadIdx.x; i < M; i += gridDim.x * 256)
    atomicAdd(&lh[(__float_as_uint(p[i]) >> 17) & 8191u], 1u);
  __syncthreads();
  unsigned* h = histC + (size_t)slot * 8192;
  for (int i = threadIdx.x; i < 8192; i += 256) {
    unsigned c = lh[i];
    if (c) atomicAdd(&h[i], c);
  }
}

__global__ __launch_bounds__(256)
void hist_fine_k(const float* __restrict__ P, const unsigned* __restrict__ sel,
                 unsigned* __restrict__ histF, TKTab t)
{
  const int slot = blockIdx.y;
  const unsigned cb = sel[slot * 8 + 0];
  const float* p = P + t.pOff[slot];
  const int M = t.M[slot];
  unsigned* h = histF + (size_t)slot * 131072;
  for (int i = blockIdx.x * 256 + threadIdx.x; i < M; i += gridDim.x * 256) {
    unsigned b = __float_as_uint(p[i]);
    if ((b >> 17) == cb) atomicAdd(&h[b & 0x1FFFFu], 1u);
  }
}

__global__ __launch_bounds__(1024)
void radix_scan_k(const unsigned* __restrict__ hist, int nbins,
                  unsigned* __restrict__ sel, TKTab t, int phase)
{
  const int slot = blockIdx.x;
  const unsigned* hb0 = hist + (size_t)slot * nbins;
  unsigned* s = sel + slot * 8;
  const int k = t.kk[slot];
  const int per = nbins / 1024;
  const int tid = threadIdx.x;
  const unsigned* hb = hb0 + tid * per;
  unsigned local = 0;
  for (int i = 0; i < per; ++i) local += hb[i];
  __shared__ unsigned part[1024];
  part[tid] = local;
  __syncthreads();
  for (int d = 1; d < 1024; d <<= 1) {
    unsigned v = (tid + d < 1024) ? part[tid + d] : 0u;
    __syncthreads();
    part[tid] += v;
    __syncthreads();
  }
  unsigned above = part[tid] - local;
  unsigned kk = (phase == 0) ? (unsigned)k : ((unsigned)k - s[1]);
  if (above < kk && above + local >= kk) {
    unsigned cum = above;
    for (int i = per - 1; i >= 0; --i) {
      unsigned c = hb[i];
      if (cum + c >= kk) {
        if (phase == 0) { s[0] = (unsigned)(tid * per + i); s[1] = cum; }
        else { s[2] = (s[0] << 17) | (unsigned)(tid * per + i); s[4] = kk - cum; }
        break;
      }
      cum += c;
    }
  }
}

__global__ __launch_bounds__(256)
void compact_k(const float* __restrict__ P, unsigned* __restrict__ sel,
               float* __restrict__ cv, unsigned* __restrict__ ci,
               unsigned* __restrict__ eq, TKTab t)
{
  const int slot = blockIdx.y;
  unsigned* s = sel + slot * 8;
  const unsigned thr = s[2];
  const float* p = P + t.pOff[slot];
  const int M = t.M[slot];
  float* cvn = cv + slot * 1024;
  unsigned* cin_ = ci + slot * 1024;
  unsigned* eqn = eq + (size_t)slot * 8192;
  for (int i = blockIdx.x * 256 + threadIdx.x; i < M; i += gridDim.x * 256) {
    unsigned b = __float_as_uint(p[i]);
    if (b > thr) {
      unsigned g = atomicAdd(&s[5], 1u);
      if (g < 1024u) { cvn[g] = p[i]; cin_[g] = (unsigned)i; }
    } else if (b == thr) {
      unsigned e = atomicAdd(&s[6], 1u);
      if (e < 8192u) eqn[e] = (unsigned)i;
    }
  }
}

__global__ __launch_bounds__(1024)
void finalize_k(const float* __restrict__ cv, const unsigned* __restrict__ ci,
                const unsigned* __restrict__ eq, const unsigned* __restrict__ sel,
                const _Float16* __restrict__ Rh, TKTab t,
                float* __restrict__ candB, float* __restrict__ candS, float* __restrict__ candC)
{
  const int slot = blockIdx.x;
  const int tid = threadIdx.x;
  const unsigned* s = sel + slot * 8;
  const float* anc = t.anc[slot];
  const int k = t.kk[slot];
  __shared__ float svals[1024];
  __shared__ unsigned sidx[1024];
  __shared__ unsigned long long key[1024];
  const unsigned cntG = s[5] < 1024u ? s[5] : 1024u;
  const unsigned nEq = s[4];
  if (tid < (int)cntG) {
    svals[tid] = cv[slot * 1024 + tid];
    sidx[tid] = ci[slot * 1024 + tid];
  }
  __syncthreads();
  if (tid == 0) {
    unsigned cnt = s[6] < 8192u ? s[6] : 8192u;
    unsigned last = 0; int first = 1;
    float tv = __uint_as_float(s[2]);
    for (unsigned e2 = 0; e2 < nEq && cntG + e2 < 1024u; ++e2) {
      unsigned best = 0xFFFFFFFFu;
      for (unsigned q = 0; q < cnt; ++q) {
        unsigned v = eq[(size_t)slot * 8192 + q];
        if ((first || v > last) && v < best) best = v;
      }
      svals[cntG + e2] = tv; sidx[cntG + e2] = best;
      last = best; first = 0;
    }
  }
  __syncthreads();
  const int kk = (int)cntG + (int)nEq;
  key[tid] = (tid < kk)
      ? (((unsigned long long)__float_as_uint(svals[tid]) << 32) |
         (unsigned long long)(0xFFFFFFFFu - sidx[tid]))
      : 0ULL;
  __syncthreads();
  for (int sz = 2; sz <= 1024; sz <<= 1) {
    for (int st = sz >> 1; st > 0; st >>= 1) {
      int ixj = tid ^ st;
      if (ixj > tid) {
        unsigned long long a = key[tid], b = key[ixj];
        bool up = ((tid & sz) == 0);
        if (up ? (a < b) : (a > b)) { key[tid] = b; key[ixj] = a; }
      }
      __syncthreads();
    }
  }
  if (tid < kk && tid < k) {
    unsigned long long kv = key[tid];
    float val = __uint_as_float((unsigned)(kv >> 32));
    unsigned idx = 0xFFFFFFFFu - (unsigned)(kv & 0xFFFFFFFFu);
    unsigned a = idx / 80u;
    unsigned cls = idx - a * 80u;
    const _Float16* rg = Rh + (size_t)t.rBase[slot] + (size_t)a * 4;
    float a0 = anc[(size_t)a * 4 + 0], a1 = anc[(size_t)a * 4 + 1];
    float a2 = anc[(size_t)a * 4 + 2], a3 = anc[(size_t)a * 4 + 3];
    float wa = a2 - a0, ha = a3 - a1;
    float xa = a0 + 0.5f * wa, ya = a1 + 0.5f * ha;
    float dx = (float)rg[0], dy = (float)rg[1];
    float dw = fminf((float)rg[2], SCALE_CLAMP_F), dh = fminf((float)rg[3], SCALE_CLAMP_F);
    float cx = dx * wa + xa, cy = dy * ha + ya;
    float wb = expf(dw) * wa, hb = expf(dh) * ha;
    float x0 = cx - 0.5f * wb, y0 = cy - 0.5f * hb;
    float x1 = cx + 0.5f * wb, y1 = cy + 0.5f * hb;
    x0 = fminf(fmaxf(x0, 0.f), IMG_W_F);
    y0 = fminf(fmaxf(y0, 0.f), IMG_H_F);
    x1 = fminf(fmaxf(x1, 0.f), IMG_W_F);
    y1 = fminf(fmaxf(y1, 0.f), IMG_H_F);
    int o = t.outBase[slot] + tid;
    candB[(size_t)o * 4 + 0] = x0; candB[(size_t)o * 4 + 1] = y0;
    candB[(size_t)o * 4 + 2] = x1; candB[(size_t)o * 4 + 3] = y1;
    candS[o] = (val > SCORE_THR) ? val : 0.f;
    candC[o] = (float)cls;
  }
}

// ---------------- class-aware NMS, one block per image ----------------
__global__ __launch_bounds__(1024)
void nms_k(const float* __restrict__ cB, const float* __restrict__ cS,
           const float* __restrict__ cC, float* __restrict__ out)
{
  const int n = blockIdx.x;
  const int tid = threadIdx.x;
  __shared__ float S[NCAND];
  __shared__ float rv[1024];
  __shared__ int ri[1024];
  __shared__ float bj[4];
  for (int i = tid; i < NCAND; i += 1024) S[i] = cS[n * NCAND + i];
  __syncthreads();
  for (int it = 0; it < MAXDET; ++it) {
    float bv = -1.f; int bix = 0;
    for (int i = tid; i < NCAND; i += 1024) {
      float v = S[i];
      if (v > bv) { bv = v; bix = i; }
    }
    rv[tid] = bv; ri[tid] = bix;
    __syncthreads();
    for (int st = 512; st > 0; st >>= 1) {
      if (tid < st) {
        float v2 = rv[tid + st]; int i2 = ri[tid + st];
        if (v2 > rv[tid] || (v2 == rv[tid] && i2 < ri[tid])) { rv[tid] = v2; ri[tid] = i2; }
      }
      __syncthreads();
    }
    const int j = ri[0];
    const float mv = rv[0];
    if (mv <= 0.f) {
      float b0 = cB[(size_t)(n * NCAND) * 4 + 0], b1 = cB[(size_t)(n * NCAND) * 4 + 1];
      float b2 = cB[(size_t)(n * NCAND) * 4 + 2], b3 = cB[(size_t)(n * NCAND) * 4 + 3];
      float c0 = cC[n * NCAND];
      for (int t2 = it + tid; t2 < MAXDET; t2 += 1024) {
        out[((size_t)n * MAXDET + t2) * 4 + 0] = b0;
        out[((size_t)n * MAXDET + t2) * 4 + 1] = b1;
        out[((size_t)n * MAXDET + t2) * 4 + 2] = b2;
        out[((size_t)n * MAXDET + t2) * 4 + 3] = b3;
        out[800 + n * MAXDET + t2] = 0.f;
        out[1000 + n * MAXDET + t2] = c0;
      }
      return;
    }
    if (tid == 0) {
      out[((size_t)n * MAXDET + it) * 4 + 0] = cB[(size_t)(n * NCAND + j) * 4 + 0];
      out[((size_t)n * MAXDET + it) * 4 + 1] = cB[(size_t)(n * NCAND + j) * 4 + 1];
      out[((size_t)n * MAXDET + it) * 4 + 2] = cB[(size_t)(n * NCAND + j) * 4 + 2];
      out[((size_t)n * MAXDET + it) * 4 + 3] = cB[(size_t)(n * NCAND + j) * 4 + 3];
      out[800 + n * MAXDET + it] = mv;
      out[1000 + n * MAXDET + it] = cC[n * NCAND + j];
      float off = cC[n * NCAND + j] * 4096.f;
      bj[0] = cB[(size_t)(n * NCAND + j) * 4 + 0] + off;
      bj[1] = cB[(size_t)(n * NCAND + j) * 4 + 1] + off;
      bj[2] = cB[(size_t)(n * NCAND + j) * 4 + 2] + off;
      bj[3] = cB[(size_t)(n * NCAND + j) * 4 + 3] + off;
    }
    __syncthreads();
    const float jx0 = bj[0], jy0 = bj[1], jx1 = bj[2], jy1 = bj[3];
    const float aj = (jx1 - jx0) * (jy1 - jy0);
    for (int i = tid; i < NCAND; i += 1024) {
      if (S[i] == 0.f) continue;
      float off = cC[n * NCAND + i] * 4096.f;
      float x0 = cB[(size_t)(n * NCAND + i) * 4 + 0] + off;
      float y0 = cB[(size_t)(n * NCAND + i) * 4 + 1] + off;
      float x1 = cB[(size_t)(n * NCAND + i) * 4 + 2] + off;
      float y1 = cB[(size_t)(n * NCAND + i) * 4 + 3] + off;
      float lx = fmaxf(jx0, x0), ly = fmaxf(jy0, y0);
      float rx = fminf(jx1, x1), ry = fminf(jy1, y1);
      float iw = fmaxf(rx - lx, 0.f), ih = fmaxf(ry - ly, 0.f);
      float inter = iw * ih;
      float ai = (x1 - x0) * (y1 - y0);
      float iou = inter / (aj + ai - inter + 1e-9f);
      if (iou > NMS_THR) S[i] = 0.f;
    }
    if (tid == 0) S[j] = 0.f;
    __syncthreads();
  }
}

// ---------------- host ----------------
extern "C" void kernel_launch(void* const* d_in, const int* in_sizes, int n_in,
                              void* d_out, int out_size, void* d_ws, size_t ws_size,
                              hipStream_t stream)
{
  static const int LH[5] = {100, 50, 25, 13, 7};
  static const int LW[5] = {152, 76, 38, 19, 10};
  static const int LHW[5] = {15200, 3800, 950, 247, 70};
  static const int NTK[5] = {1000, 1000, 1000, 1000, 630};
  static const int OFFS[5] = {0, 1000, 2000, 3000, 4000};
  static const unsigned ACTOFF[5] = {0u, 8042496u, 10119168u, 10672128u, 10833408u};
  static const int CUMT[6] = {0, 475, 594, 624, 632, 635};
  static const int CUMR[6] = {0, 100, 150, 175, 188, 195};
  static const int ROFF[5] = {0, 1094400, 1368000, 1436400, 1454184};
  // P offsets for the L1-4 both-image batch
  static const int POFF14[4] = {0, 2736000, 3420000, 3597840};
  static const int PSTRIDE14 = 3648240;

  const float* feat[5]; const float* anc[5];
  for (int l = 0; l < 5; ++l) {
    feat[l] = (const float*)d_in[l];
    anc[l] = (const float*)d_in[13 + l];
  }
  const float* csw = (const float*)d_in[5];
  const float* csb = (const float*)d_in[6];
  const float* bsw = (const float*)d_in[7];
  const float* bsb = (const float*)d_in[8];
  const float* scw = (const float*)d_in[9];
  const float* scb = (const float*)d_in[10];
  const float* bpw = (const float*)d_in[11];
  const float* bpb = (const float*)d_in[12];

  float* ws = (float*)d_ws;
  size_t o = 0;
  _Float16* actBase = (_Float16*)(ws + o); o += (size_t)4 * BUF_HALFS / 2;  // 87.1MB
  _Float16* wpk = (_Float16*)(ws + o); o += 3317760;                        // 13.3MB
  float* P = ws + o; o += 10944000;                                         // 43.8MB
  _Float16* Rh = (_Float16*)(ws + o); o += 729612;                          // 2.9MB
  float* candB = ws + o; o += (size_t)NIMG * NCAND * 4;
  float* candS = ws + o; o += NIMG * NCAND;
  float* candC = ws + o; o += NIMG * NCAND;
  float* candV = ws + o; o += 8 * 1024;
  unsigned* candI = (unsigned*)(ws + o); o += 8 * 1024;
  unsigned* eqI = (unsigned*)(ws + o); o += 8 * 8192;
  unsigned* histC = (unsigned*)(ws + o); o += 8 * 8192;
  unsigned* histF = (unsigned*)(ws + o); o += (size_t)8 * 131072;
  unsigned* sel = (unsigned*)(ws + o); o += 8 * 8;
  if (ws_size < o * sizeof(float)) return;  // ~152 MB required

  _Float16* X = actBase;
  _Float16* A = X + BUF_HALFS;
  _Float16* B = A + BUF_HALFS;
  _Float16* C = B + BUF_HALFS;
  float* out = (float*)d_out;

  // weight prepack
  for (int i = 0; i < 4; ++i) {
    int tot = 9 * 16 * 8 * 64;
    prepack_k<<<dim3((tot + 255) / 256), dim3(256), 0, stream>>>(
        csw + (size_t)i * 589824, wpk + WOFF_CLS_T(i), 256, 8);
    prepack_k<<<dim3((tot + 255) / 256), dim3(256), 0, stream>>>(
        bsw + (size_t)i * 589824, wpk + WOFF_BBX_T(i), 256, 8);
  }
  {
    int tot = 9 * 16 * 24 * 64;
    prepack_k<<<dim3((tot + 255) / 256), dim3(256), 0, stream>>>(scw, wpk + WOFF_CLS_H, 720, 24);
    tot = 9 * 16 * 2 * 64;
    prepack_k<<<dim3((tot + 255) / 256), dim3(256), 0, stream>>>(bpw, wpk + WOFF_BBX_H, 36, 2);
  }

  hipMemsetAsync(actBase, 0, (size_t)4 * BUF_HALFS * 2, stream);

  // tables
  ConvTab ct;
  CvtTab vt;
  for (int l = 0; l < 5; ++l) {
    ct.H[l] = LH[l]; ct.W[l] = LW[l]; ct.actOff[l] = ACTOFF[l];
    vt.f[l] = feat[l]; vt.H[l] = LH[l]; vt.W[l] = LW[l]; vt.actOff[l] = ACTOFF[l];
  }
  for (int i = 0; i < 6; ++i) { ct.cum[i] = CUMT[i]; vt.cumR[i] = CUMR[i]; }

  convert_k<<<dim3(195, NIMG), dim3(256), 0, stream>>>(X, vt);

  // towers: (X,X)->(A,B); (A,B)->(C,X); (C,X)->(A,B); (A,B)->(C,X)
  tower_k<<<dim3(635, 8), dim3(64), 0, stream>>>(X, X, wpk, csb + 0, bsb + 0, A, B,
      WOFF_CLS_T(0), WOFF_BBX_T(0), ct);
  tower_k<<<dim3(635, 8), dim3(64), 0, stream>>>(A, B, wpk, csb + 256, bsb + 256, C, X,
      WOFF_CLS_T(1), WOFF_BBX_T(1), ct);
  tower_k<<<dim3(635, 8), dim3(64), 0, stream>>>(C, X, wpk, csb + 512, bsb + 512, A, B,
      WOFF_CLS_T(2), WOFF_BBX_T(2), ct);
  tower_k<<<dim3(635, 8), dim3(64), 0, stream>>>(A, B, wpk, csb + 768, bsb + 768, C, X,
      WOFF_CLS_T(3), WOFF_BBX_T(3), ct);

  // ---- 3 head+topk batches ----
  auto runTopk = [&](const TKTab& tk, int nslot) {
    hipMemsetAsync(histC, 0, (size_t)nslot * 8192 * 4, stream);
    hipMemsetAsync(histF, 0, (size_t)nslot * 131072 * 4, stream);
    hipMemsetAsync(sel, 0, (size_t)nslot * 32, stream);
    hist_coarse_k<<<dim3(128, nslot), dim3(256), 0, stream>>>(P, histC, tk);
    radix_scan_k<<<dim3(nslot), dim3(1024), 0, stream>>>(histC, 8192, sel, tk, 0);
    hist_fine_k<<<dim3(128, nslot), dim3(256), 0, stream>>>(P, sel, histF, tk);
    radix_scan_k<<<dim3(nslot), dim3(1024), 0, stream>>>(histF, 131072, sel, tk, 1);
    compact_k<<<dim3(128, nslot), dim3(256), 0, stream>>>(P, sel, candV, candI, eqI, tk);
    finalize_k<<<dim3(nslot), dim3(1024), 0, stream>>>(candV, candI, eqI, sel, Rh, tk,
                                                       candB, candS, candC);
  };

  // L0, per image
  for (int n = 0; n < NIMG; ++n) {
    HeadTab ht = {};
    ht.cum[0] = 0; ht.cum[1] = 238;
    for (int i = 2; i < 6; ++i) ht.cum[i] = 0x7FFFFFFF;
    ht.actOff[0] = ACTOFF[0]; ht.H[0] = LH[0]; ht.W[0] = LW[0];
    ht.pOffL[0] = 0; ht.rOffL[0] = ROFF[0];
    ht.imgBase = n; ht.pImgStride = 0;
    head_k<<<dim3(238, 13, 1), dim3(64), 0, stream>>>(C, X, wpk, scb, bpb, P, Rh, ht);
    TKTab tk = {};
    tk.pOff[0] = 0; tk.M[0] = LHW[0] * 720; tk.kk[0] = NTK[0];
    tk.rBase[0] = ROFF[0] + n * LHW[0] * 36;
    tk.outBase[0] = n * NCAND + OFFS[0];
    tk.anc[0] = anc[0];
    runTopk(tk, 1);
  }
  // levels 1-4, both images
  {
    HeadTab ht = {};
    static const int CUMH14[6] = {0, 60, 75, 79, 81, 0x7FFFFFFF};
    for (int i = 0; i < 6; ++i) ht.cum[i] = CUMH14[i];
    for (int i = 0; i < 4; ++i) {
      int l = i + 1;
      ht.actOff[i] = ACTOFF[l]; ht.H[i] = LH[l]; ht.W[i] = LW[l];
      ht.pOffL[i] = POFF14[i]; ht.rOffL[i] = ROFF[l];
    }
    ht.imgBase = 0; ht.pImgStride = PSTRIDE14;
    head_k<<<dim3(81, 13, 2), dim3(64), 0, stream>>>(C, X, wpk, scb, bpb, P, Rh, ht);
    TKTab tk = {};
    for (int s = 0; s < 8; ++s) {
      int l = (s & 3) + 1, n = s >> 2;
      tk.pOff[s] = n * PSTRIDE14 + POFF14[s & 3];
      tk.M[s] = LHW[l] * 720;
      tk.kk[s] = NTK[l];
      tk.rBase[s] = ROFF[l] + n * LHW[l] * 36;
      tk.outBase[s] = n * NCAND + OFFS[l];
      tk.anc[s] = anc[l];
    }
    runTopk(tk, 8);
  }
  nms_k<<<dim3(NIMG), dim3(1024), 0, stream>>>(candB, candS, candC, out);
}